// Round 7
// baseline (966.053 us; speedup 1.0000x reference)
//
#include <hip/hip_runtime.h>

typedef unsigned short u16;
typedef __bf16 bf16x8 __attribute__((ext_vector_type(8)));
typedef float f32x4 __attribute__((ext_vector_type(4)));
typedef float f32x2 __attribute__((ext_vector_type(2)));
typedef u16 u16x4 __attribute__((ext_vector_type(4)));
typedef u16 u16x8 __attribute__((ext_vector_type(8)));

// Problem constants
#define SEQ   4096
#define DM    1024
#define DI    2048
#define NTOK  8192      // BATCH * SEQ
#define NXP   68        // DT_RANK + 2*D_STATE
#define DTR   64        // DT_RANK
#define NCH   4096      // BATCH * DI channels for scan
#define CHUNK 32
#define NCHK  128       // SEQ / CHUNK

__device__ __forceinline__ float bf2f(u16 v) {
  union { unsigned u; float f; } x; x.u = ((unsigned)v) << 16; return x.f;
}
__device__ __forceinline__ u16 f2bf(float f) {
  unsigned u = __float_as_uint(f);
  return (u16)((u + 0x7FFFu + ((u >> 16) & 1u)) >> 16);   // RNE
}

// ---------------------------------------------------------------------------
// Input dtype detection (f32 inputs -> low u16 has huge bf16 exponents)
// ---------------------------------------------------------------------------
__global__ __launch_bounds__(256)
void detect_kernel(const u16* __restrict__ x, int* __restrict__ flag)
{
  __shared__ int tot;
  if (threadIdx.x == 0) tot = 0;
  __syncthreads();
  int cnt = 0;
  for (int i = threadIdx.x; i < 4096; i += 256) {
    const int e = (x[2 * i] >> 7) & 0xFF;
    if (e > 167) cnt++;
  }
  atomicAdd(&tot, cnt);
  __syncthreads();
  if (threadIdx.x == 0) flag[0] = (tot >= 8) ? 1 : 0;
}

// All 6 big weights in ONE launch, 8 elems/thread; NO-OP when inputs are bf16.
#define NW0 4194304   // w_in
#define NW1  139264   // w_xproj
#define NW2  131072   // w_dt
#define NW3 2097152   // w_out
#define NW4 1048576   // ffn_w1
#define NW5 1048576   // ffn_w2
__global__ __launch_bounds__(256)
void convert_big(const float* __restrict__ s0, const float* __restrict__ s1,
                 const float* __restrict__ s2, const float* __restrict__ s3,
                 const float* __restrict__ s4, const float* __restrict__ s5,
                 u16* __restrict__ d0, u16* __restrict__ d1, u16* __restrict__ d2,
                 u16* __restrict__ d3, u16* __restrict__ d4, u16* __restrict__ d5,
                 const int* __restrict__ flag)
{
  if (*flag == 0) return;
  long e = ((long)blockIdx.x * 256 + threadIdx.x) * 8;
  const long c1 = NW0, c2 = c1 + NW1, c3 = c2 + NW2, c4 = c3 + NW3,
             c5 = c4 + NW4, c6 = c5 + NW5;
  if (e >= c6) return;
  const float* s; u16* d;
  if      (e < c1) { s = s0;          d = d0; }
  else if (e < c2) { s = s1; e -= c1; d = d1; }
  else if (e < c3) { s = s2; e -= c2; d = d2; }
  else if (e < c4) { s = s3; e -= c3; d = d3; }
  else if (e < c5) { s = s4; e -= c4; d = d4; }
  else             { s = s5; e -= c5; d = d5; }
  f32x4 a = *(const f32x4*)(s + e);
  f32x4 b = *(const f32x4*)(s + e + 4);
  u16x8 o;
#pragma unroll
  for (int k = 0; k < 4; ++k) { o[k] = f2bf(a[k]); o[4 + k] = f2bf(b[k]); }
  *(u16x8*)(d + e) = o;
}

// All 11 small vectors in one launch; conv_w stored TRANSPOSED [4][DI].
__global__ __launch_bounds__(256)
void convert_small_kernel(const void* s0, const void* s1, const void* s2,
                          const void* s3, const void* s4, const void* s5,
                          const void* s6, const void* s7, const void* s8,
                          const void* s9, const void* s10,
                          u16* __restrict__ dst, const int* __restrict__ flag)
{
  const int i = blockIdx.x * 256 + threadIdx.x;
  if (i >= 24576) return;
  const void* src; int off; int dsti = i;
  if      (i < 8192)  { src = s0;  off = i;
                        dsti = (off & 3) * DI + (off >> 2); }  // conv_w -> [j][d]
  else if (i < 10240) { src = s1;  off = i - 8192; }   // conv_b
  else if (i < 12288) { src = s2;  off = i - 10240; }  // b_dt
  else if (i < 16384) { src = s3;  off = i - 12288; }  // a_log
  else if (i < 18432) { src = s4;  off = i - 16384; }  // d_skip
  else if (i < 19456) { src = s5;  off = i - 18432; }  // ln1_g
  else if (i < 20480) { src = s6;  off = i - 19456; }  // ln1_b
  else if (i < 21504) { src = s7;  off = i - 20480; }  // ln2_g
  else if (i < 22528) { src = s8;  off = i - 21504; }  // ln2_b
  else if (i < 23552) { src = s9;  off = i - 22528; }  // ffn_b1
  else                { src = s10; off = i - 23552; }  // ffn_b2
  dst[dsti] = (*flag) ? f2bf(((const float*)src)[off]) : ((const u16*)src)[off];
}

// ---------------------------------------------------------------------------
// LayerNorm: 2 rows per block, 8 elems per thread, vectorized loads/stores.
// ---------------------------------------------------------------------------
template<bool DUAL>
__global__ __launch_bounds__(256)
void ln_kernel(const void* __restrict__ xin, const u16* __restrict__ gw,
               const u16* __restrict__ bw, u16* __restrict__ outp,
               const int* __restrict__ flag)
{
  const int tid = threadIdx.x;
  const int sub = tid >> 7;                  // row within block
  const int col0 = (tid & 127) * 8;
  const int row = blockIdx.x * 2 + sub;
  const bool isf32 = DUAL ? (*flag != 0) : true;
  float v[8];
  if (isf32) {
    const float* xf = (const float*)xin + (size_t)row * DM + col0;
    f32x4 a = *(const f32x4*)xf, b2 = *(const f32x4*)(xf + 4);
#pragma unroll
    for (int k = 0; k < 4; ++k) { v[k] = a[k]; v[4 + k] = b2[k]; }
  } else {
    u16x8 xb = *(const u16x8*)((const u16*)xin + (size_t)row * DM + col0);
#pragma unroll
    for (int k = 0; k < 8; ++k) v[k] = bf2f(xb[k]);
  }
  float s = 0.f, s2 = 0.f;
#pragma unroll
  for (int k = 0; k < 8; ++k) { s += v[k]; s2 += v[k] * v[k]; }
#pragma unroll
  for (int off = 32; off > 0; off >>= 1) {
    s  += __shfl_down(s,  off);
    s2 += __shfl_down(s2, off);
  }
  __shared__ float red[4], red2[4];
  __shared__ f32x2 stat[2];
  const int wv = tid >> 6;
  if ((tid & 63) == 0) { red[wv] = s; red2[wv] = s2; }
  __syncthreads();
  if ((tid & 127) == 0) {
    float ts = red[sub * 2] + red[sub * 2 + 1];
    float t2 = red2[sub * 2] + red2[sub * 2 + 1];
    float mu = ts * (1.f / DM);
    float var = t2 * (1.f / DM) - mu * mu;
    stat[sub] = f32x2{mu, rsqrtf(var + 1e-5f)};
  }
  __syncthreads();
  const float mu = stat[sub][0], rs = stat[sub][1];
  u16x8 gv = *(const u16x8*)(gw + col0), bv = *(const u16x8*)(bw + col0);
  u16x8 o;
#pragma unroll
  for (int k = 0; k < 8; ++k)
    o[k] = f2bf((v[k] - mu) * rs * bf2f(gv[k]) + bf2f(bv[k]));
  *(u16x8*)(outp + (size_t)row * DM + col0) = o;
}

// lgkm-only wait + raw barrier (NO vmcnt drain: global loads stay in flight).
// 0xc07f = vmcnt(63) expcnt(7) lgkmcnt(0).
#define LGKM_BARRIER() do {                         \
    __asm__ __volatile__("" ::: "memory");          \
    __builtin_amdgcn_s_waitcnt(0xc07f);             \
    __builtin_amdgcn_s_barrier();                   \
    __asm__ __volatile__("" ::: "memory");          \
  } while (0)

// ---------------------------------------------------------------------------
// bf16 MFMA GEMM: C[M,N] = A[M,K] @ B[N,K]^T.  128x128 tile, BK=32.
// 3-stage register-staged pipeline (AITER-style): compute tile k from LDS,
// ds_write tile k+1 from VGPRs, global-load tile k+2 into VGPRs. Barrier is
// lgkm-only, so tile k+2 loads remain in flight across it (no vmcnt(0) drain).
// Global fetch is NATURAL lane order (coalesced); the anti-bank-conflict XOR
// swizzle is applied on the ds_write side (per-lane scatter), read with q^rsw.
// Requires: M%128==0, N%128==0, K%64==0, gridDim.x == (N/128)*64, N/128==1<<LNBX.
// EPI: 1 bf16 | 2 +bias,softplus->bf16 | 3 +x(flag dtype)->f32 |
//      4 +bias,relu->bf16 | 5 +bias+addf32 -> out(bf16/f32 per flag) |
//      6 split store: col<DI -> Cp (bf16), else -> Cp2 (bf16), row stride DI
// ---------------------------------------------------------------------------
template<int EPI, int LNBX>
__global__ __launch_bounds__(256, 3)
void gemm_kernel(const u16* __restrict__ A, const u16* __restrict__ Bc,
                 const u16* __restrict__ Braw,
                 int M, int N, int K,
                 const u16* __restrict__ bias, const u16* __restrict__ addbf,
                 const float* __restrict__ addf, const int* __restrict__ dtflag,
                 void* __restrict__ Cp, void* __restrict__ Cp2)
{
  __shared__ __align__(16) u16 sA[2][128 * 32];
  __shared__ __align__(16) u16 sB[2][128 * 32];
  const int fl = *dtflag;
  const u16* __restrict__ B = fl ? Bc : Braw;
  const int tid = threadIdx.x;
  const int b = blockIdx.x;
  const int xcd = b & 7;
  const int kk = b >> 3;
  const int bx = kk & ((1 << LNBX) - 1);
  const int by = xcd * 8 + (kk >> LNBX);
  const int m0 = by * 128;
  const int n0 = bx * 128;
  const int lane = tid & 63;
  const int wv = tid >> 6;
  const int wm = (wv & 1) * 64;
  const int wn = (wv >> 1) * 64;
  const int r = lane & 15;
  const int q = lane >> 4;
  const int rsw = (r >> 1) & 3;        // read-side bank swizzle

  const int pr = lane >> 2;            // 0..15 row in 16-row staging chunk
  const int pkN = (lane & 3) * 8;      // NATURAL global fetch column
  const int wcol = (((lane & 3) ^ ((pr >> 1) & 3)) * 8);  // swizzled LDS col
  const int wo0 = (wv * 2 + 0) * 512 + pr * 32 + wcol;
  const int wo1 = wo0 + 512;
  const u16* gA0 = A + (size_t)(m0 + wv * 32 + pr) * K + pkN;
  const u16* gA1 = gA0 + (size_t)16 * K;
  const u16* gB0 = B + (size_t)(n0 + wv * 32 + pr) * K + pkN;
  const u16* gB1 = gB0 + (size_t)16 * K;

  f32x4 acc[4][4];
#pragma unroll
  for (int i = 0; i < 4; ++i)
#pragma unroll
    for (int j = 0; j < 4; ++j)
#pragma unroll
      for (int t = 0; t < 4; ++t) acc[i][j][t] = 0.f;

  uint4 rg[2][4];
#define LOADT(s) { rg[s][0] = *(const uint4*)gA0; rg[s][1] = *(const uint4*)gA1;  \
                   rg[s][2] = *(const uint4*)gB0; rg[s][3] = *(const uint4*)gB1;  \
                   gA0 += 32; gA1 += 32; gB0 += 32; gB1 += 32; }
#define STORET(s, bb) { *(uint4*)&sA[bb][wo0] = rg[s][0]; *(uint4*)&sA[bb][wo1] = rg[s][1]; \
                        *(uint4*)&sB[bb][wo0] = rg[s][2]; *(uint4*)&sB[bb][wo1] = rg[s][3]; }
#define PHASE(k, cur) {                                                              \
    LGKM_BARRIER();                                                                  \
    bf16x8 af[4], bfr[4];                                                            \
    _Pragma("unroll")                                                                \
    for (int i = 0; i < 4; ++i)                                                      \
      af[i] = *(const bf16x8*)&sA[cur][(wm + i * 16 + r) * 32 + (q ^ rsw) * 8];      \
    _Pragma("unroll")                                                                \
    for (int j = 0; j < 4; ++j)                                                      \
      bfr[j] = *(const bf16x8*)&sB[cur][(wn + j * 16 + r) * 32 + (q ^ rsw) * 8];     \
    if ((k) + 2 < nk) LOADT(cur);                                                    \
    if ((k) + 1 < nk) STORET((cur) ^ 1, (cur) ^ 1);                                  \
    _Pragma("unroll")                                                                \
    for (int i = 0; i < 4; ++i)                                                      \
      _Pragma("unroll")                                                              \
      for (int j = 0; j < 4; ++j)                                                    \
        acc[i][j] = __builtin_amdgcn_mfma_f32_16x16x32_bf16(af[i], bfr[j], acc[i][j], 0, 0, 0); \
  }

  const int nk = K >> 5;               // even for all call sites (K%64==0)
  LOADT(0);                            // tile 0 -> regs
  STORET(0, 0);                        // tile 0 -> LDS[0] (vmcnt auto-wait)
  if (nk > 1) LOADT(1);                // tile 1 -> regs (in flight)
  for (int kt = 0; kt < nk; kt += 2) { PHASE(kt, 0); PHASE(kt + 1, 1); }
#undef PHASE
#undef STORET
#undef LOADT

  // epilogue: D row = wm+i*16+q*4+t (M), col = wn+j*16+r (N)
#pragma unroll
  for (int i = 0; i < 4; ++i) {
#pragma unroll
    for (int j = 0; j < 4; ++j) {
#pragma unroll
      for (int t = 0; t < 4; ++t) {
        const int row = m0 + wm + i * 16 + q * 4 + t;
        const int col = n0 + wn + j * 16 + r;
        float v = acc[i][j][t];
        if (EPI == 6) {
          const size_t rb = (size_t)row * DI;
          if (col < DI) ((u16*)Cp)[rb + col] = f2bf(v);
          else          ((u16*)Cp2)[rb + col - DI] = f2bf(v);
        } else {
          const size_t idx = (size_t)row * N + col;
          if (EPI == 1) {
            ((u16*)Cp)[idx] = f2bf(v);
          } else if (EPI == 2) {           // dt = softplus(v + b_dt)
            v += bf2f(bias[col]);
            v = (v > 15.f) ? v : __logf(1.f + __expf(v));
            ((u16*)Cp)[idx] = f2bf(v);
          } else if (EPI == 3) {           // h = x + mamba_out (f32)
            v += fl ? addf[idx] : bf2f(addbf[idx]);
            ((float*)Cp)[idx] = v;
          } else if (EPI == 4) {           // relu(v + b1)
            v += bf2f(bias[col]);
            ((u16*)Cp)[idx] = f2bf(fmaxf(v, 0.f));
          } else {                         // out = h + v + b2
            v += bf2f(bias[col]) + addf[idx];
            if (fl) ((float*)Cp)[idx] = v;
            else    ((u16*)Cp)[idx] = f2bf(v);
          }
        }
      }
    }
  }
}

// ---------------------------------------------------------------------------
// x_proj split-K: part[z] = u[:, z*256:(z+1)*256] @ w_xproj[:, same]^T
// grid (8, 64). Output f32 partials [8, NTOK, 68]. Same 3-stage pipeline.
// ---------------------------------------------------------------------------
__global__ __launch_bounds__(256, 3)
void xproj_splitk(const u16* __restrict__ A, const u16* __restrict__ Bc,
                  const u16* __restrict__ Braw, const int* __restrict__ dtflag,
                  float* __restrict__ part)
{
  __shared__ __align__(16) u16 sA[2][128 * 32];
  __shared__ __align__(16) u16 sB[2][128 * 32];
  const int fl = *dtflag;
  const u16* __restrict__ B = fl ? Bc : Braw;
  const int tid = threadIdx.x;
  const int kz = blockIdx.x;           // 0..7
  const int m0 = blockIdx.y * 128;
  const int kbase = kz * 256;
  const int lane = tid & 63;
  const int wv = tid >> 6;
  const int wm = (wv & 1) * 64;
  const int wn = (wv >> 1) * 64;
  const int r = lane & 15;
  const int q = lane >> 4;
  const int rsw = (r >> 1) & 3;
  const int pr = lane >> 2;
  const int pkN = (lane & 3) * 8;
  const int wcol = (((lane & 3) ^ ((pr >> 1) & 3)) * 8);
  const int wo0 = (wv * 2 + 0) * 512 + pr * 32 + wcol;
  const int wo1 = wo0 + 512;

  int br0 = wv * 32 + pr;      if (br0 > 67) br0 = 67;   // junk cols unused
  int br1 = wv * 32 + 16 + pr; if (br1 > 67) br1 = 67;
  const u16* gA0 = A + (size_t)(m0 + wv * 32 + pr) * DI + kbase + pkN;
  const u16* gA1 = gA0 + (size_t)16 * DI;
  const u16* gB0 = B + (size_t)br0 * DI + kbase + pkN;
  const u16* gB1 = B + (size_t)br1 * DI + kbase + pkN;

  f32x4 acc[4][4];
#pragma unroll
  for (int i = 0; i < 4; ++i)
#pragma unroll
    for (int j = 0; j < 4; ++j)
#pragma unroll
      for (int t = 0; t < 4; ++t) acc[i][j][t] = 0.f;

  uint4 rg[2][4];
#define LOADT(s) { rg[s][0] = *(const uint4*)gA0; rg[s][1] = *(const uint4*)gA1;  \
                   rg[s][2] = *(const uint4*)gB0; rg[s][3] = *(const uint4*)gB1;  \
                   gA0 += 32; gA1 += 32; gB0 += 32; gB1 += 32; }
#define STORET(s, bb) { *(uint4*)&sA[bb][wo0] = rg[s][0]; *(uint4*)&sA[bb][wo1] = rg[s][1]; \
                        *(uint4*)&sB[bb][wo0] = rg[s][2]; *(uint4*)&sB[bb][wo1] = rg[s][3]; }
#define PHASE(k, cur) {                                                              \
    LGKM_BARRIER();                                                                  \
    bf16x8 af[4], bfr[4];                                                            \
    _Pragma("unroll")                                                                \
    for (int i = 0; i < 4; ++i)                                                      \
      af[i] = *(const bf16x8*)&sA[cur][(wm + i * 16 + r) * 32 + (q ^ rsw) * 8];      \
    _Pragma("unroll")                                                                \
    for (int j = 0; j < 4; ++j)                                                      \
      bfr[j] = *(const bf16x8*)&sB[cur][(wn + j * 16 + r) * 32 + (q ^ rsw) * 8];     \
    if ((k) + 2 < 8) LOADT(cur);                                                     \
    if ((k) + 1 < 8) STORET((cur) ^ 1, (cur) ^ 1);                                   \
    _Pragma("unroll")                                                                \
    for (int i = 0; i < 4; ++i)                                                      \
      _Pragma("unroll")                                                              \
      for (int j = 0; j < 4; ++j)                                                    \
        acc[i][j] = __builtin_amdgcn_mfma_f32_16x16x32_bf16(af[i], bfr[j], acc[i][j], 0, 0, 0); \
  }

  LOADT(0);
  STORET(0, 0);
  LOADT(1);
  for (int kt = 0; kt < 8; kt += 2) { PHASE(kt, 0); PHASE(kt + 1, 1); }
#undef PHASE
#undef STORET
#undef LOADT

#pragma unroll
  for (int i = 0; i < 4; ++i)
#pragma unroll
    for (int j = 0; j < 4; ++j)
#pragma unroll
      for (int t = 0; t < 4; ++t) {
        const int row = m0 + wm + i * 16 + q * 4 + t;
        const int col = wn + j * 16 + r;
        if (col < NXP)
          part[((size_t)kz * NTOK + row) * NXP + col] = acc[i][j][t];
      }
}

// Reduce partials: cols 0..63 -> dtraw bf16 [NTOK,64]; 64..67 -> bc f32 [NTOK,4]
__global__ __launch_bounds__(256)
void xreduce_kernel(const float* __restrict__ part, u16* __restrict__ dtraw,
                    float* __restrict__ bc)
{
  const int i = blockIdx.x * 256 + threadIdx.x;
  if (i >= NTOK * NXP) return;
  const int row = i / NXP, col = i - row * NXP;
  float s = 0.f;
#pragma unroll
  for (int z = 0; z < 8; ++z) s += part[(size_t)z * NTOK * NXP + i];
  if (col < DTR) dtraw[(size_t)row * DTR + col] = f2bf(s);
  else           bc[row * 4 + (col - DTR)] = s;
}

// ---------------------------------------------------------------------------
// Depthwise causal conv (k=4, transposed weights) + bias + SiLU, x8 vectorized.
// ---------------------------------------------------------------------------
__global__ __launch_bounds__(256)
void conv_silu_kernel(const u16* __restrict__ xp, const u16* __restrict__ cwT,
                      const u16* __restrict__ cb, u16* __restrict__ u)
{
  const int token = blockIdx.x;
  const int t = token & (SEQ - 1);
  const int d0 = threadIdx.x * 8;
  const ptrdiff_t base = (ptrdiff_t)token * DI + d0;
  float acc[8];
  u16x8 cbv = *(const u16x8*)(cb + d0);
#pragma unroll
  for (int k = 0; k < 8; ++k) acc[k] = bf2f(cbv[k]);
#pragma unroll
  for (int j = 0; j < 4; ++j) {
    if (t - 3 + j >= 0) {
      u16x8 xv = *(const u16x8*)(xp + base + (ptrdiff_t)(j - 3) * DI);
      u16x8 wv = *(const u16x8*)(cwT + j * DI + d0);
#pragma unroll
      for (int k = 0; k < 8; ++k) acc[k] += bf2f(wv[k]) * bf2f(xv[k]);
    }
  }
  u16x8 o;
#pragma unroll
  for (int k = 0; k < 8; ++k) {
    const float sg = 1.f / (1.f + __expf(-acc[k]));
    o[k] = f2bf(acc[k] * sg);
  }
  *(u16x8*)(u + base) = o;
}

// ---------------------------------------------------------------------------
// Chunked SSM scan (N=2 states), 4 channels per thread, CHUNK=32.
// ---------------------------------------------------------------------------
__global__ __launch_bounds__(256)
void scan_pass1(const u16* __restrict__ dtb, const u16* __restrict__ ub,
                const float* __restrict__ bc, const u16* __restrict__ a_log,
                float* __restrict__ S, float* __restrict__ hf0, float* __restrict__ hf1)
{
  const int g4 = blockIdx.x * 256 + threadIdx.x;   // NCHK*NCH/4
  const int chg = g4 & (NCH / 4 - 1);
  const int c = g4 >> 10;
  const int ch0 = chg * 4;
  const int b = ch0 >> 11;
  const int d0 = ch0 & (DI - 1);
  u16x8 av = *(const u16x8*)(a_log + d0 * 2);
  float A0[4], A1[4];
#pragma unroll
  for (int k = 0; k < 4; ++k) {
    A0[k] = -__expf(bf2f(av[2 * k]));
    A1[k] = -__expf(bf2f(av[2 * k + 1]));
  }
  float h0[4] = {0.f, 0.f, 0.f, 0.f}, h1[4] = {0.f, 0.f, 0.f, 0.f};
  float s[4] = {0.f, 0.f, 0.f, 0.f};
  const int row0 = b * SEQ + c * CHUNK;
  for (int i = 0; i < CHUNK; ++i) {
    const size_t row = row0 + i;
    u16x4 dtv = *(const u16x4*)(dtb + row * DI + d0);
    u16x4 uv  = *(const u16x4*)(ub + row * DI + d0);
    f32x2 Bv = *(const f32x2*)(bc + row * 4);
#pragma unroll
    for (int k = 0; k < 4; ++k) {
      const float dt = bf2f(dtv[k]);
      const float dtu = dt * bf2f(uv[k]);
      h0[k] = __expf(A0[k] * dt) * h0[k] + dtu * Bv[0];
      h1[k] = __expf(A1[k] * dt) * h1[k] + dtu * Bv[1];
      s[k] += dt;
    }
  }
  const size_t g0 = (size_t)c * NCH + ch0;
  *(f32x4*)(S + g0)   = f32x4{s[0], s[1], s[2], s[3]};
  *(f32x4*)(hf0 + g0) = f32x4{h0[0], h0[1], h0[2], h0[3]};
  *(f32x4*)(hf1 + g0) = f32x4{h1[0], h1[1], h1[2], h1[3]};
}

__global__ __launch_bounds__(256)
void scan_pass2(const float* __restrict__ S, const float* __restrict__ hf0,
                const float* __restrict__ hf1, const u16* __restrict__ a_log,
                float* __restrict__ hi0, float* __restrict__ hi1)
{
  const int ch = blockIdx.x * 256 + threadIdx.x;  // NCH
  const int d = ch & (DI - 1);
  const float A0 = -__expf(bf2f(a_log[d * 2 + 0]));
  const float A1 = -__expf(bf2f(a_log[d * 2 + 1]));
  float h0 = 0.f, h1 = 0.f;
  for (int c = 0; c < NCHK; ++c) {
    const size_t g = (size_t)c * NCH + ch;
    hi0[g] = h0; hi1[g] = h1;
    const float s = S[g];
    h0 = __expf(A0 * s) * h0 + hf0[g];
    h1 = __expf(A1 * s) * h1 + hf1[g];
  }
}

__global__ __launch_bounds__(256)
void scan_pass3(const u16* __restrict__ dtb, const u16* __restrict__ ub,
                const float* __restrict__ bc, const u16* __restrict__ zbuf,
                const u16* __restrict__ a_log, const u16* __restrict__ d_skip,
                const float* __restrict__ hi0, const float* __restrict__ hi1,
                u16* __restrict__ yb)
{
  const int g4 = blockIdx.x * 256 + threadIdx.x;
  const int chg = g4 & (NCH / 4 - 1);
  const int c = g4 >> 10;
  const int ch0 = chg * 4;
  const int b = ch0 >> 11;
  const int d0 = ch0 & (DI - 1);
  u16x8 av = *(const u16x8*)(a_log + d0 * 2);
  u16x4 dkv = *(const u16x4*)(d_skip + d0);
  float A0[4], A1[4], dsk[4];
#pragma unroll
  for (int k = 0; k < 4; ++k) {
    A0[k] = -__expf(bf2f(av[2 * k]));
    A1[k] = -__expf(bf2f(av[2 * k + 1]));
    dsk[k] = bf2f(dkv[k]);
  }
  const size_t g0 = (size_t)c * NCH + ch0;
  f32x4 h0v = *(const f32x4*)(hi0 + g0);
  f32x4 h1v = *(const f32x4*)(hi1 + g0);
  float h0[4], h1[4];
#pragma unroll
  for (int k = 0; k < 4; ++k) { h0[k] = h0v[k]; h1[k] = h1v[k]; }
  const int row0 = b * SEQ + c * CHUNK;
  for (int i = 0; i < CHUNK; ++i) {
    const size_t row = row0 + i;
    u16x4 dtv = *(const u16x4*)(dtb + row * DI + d0);
    u16x4 uv  = *(const u16x4*)(ub + row * DI + d0);
    u16x4 zv  = *(const u16x4*)(zbuf + row * DI + d0);
    f32x4 bcv = *(const f32x4*)(bc + row * 4);
    u16x4 o;
#pragma unroll
    for (int k = 0; k < 4; ++k) {
      const float dt = bf2f(dtv[k]);
      const float uu = bf2f(uv[k]);
      const float dtu = dt * uu;
      h0[k] = __expf(A0[k] * dt) * h0[k] + dtu * bcv[0];
      h1[k] = __expf(A1[k] * dt) * h1[k] + dtu * bcv[1];
      const float y = h0[k] * bcv[2] + h1[k] * bcv[3];
      const float z = bf2f(zv[k]);
      const float sz = z / (1.f + __expf(-z));
      o[k] = f2bf((y + dsk[k] * uu) * sz);
    }
    *(u16x4*)(yb + row * DI + d0) = o;    // in-place over dtb: ok
  }
}

// ---------------------------------------------------------------------------
extern "C" void kernel_launch(void* const* d_in, const int* in_sizes, int n_in,
                              void* d_out, int out_size, void* d_ws, size_t ws_size,
                              hipStream_t stream)
{
  const void* x       = d_in[0];
  const void* w_in    = d_in[1];
  const void* conv_w  = d_in[2];
  const void* conv_b  = d_in[3];
  const void* w_xproj = d_in[4];
  const void* w_dt    = d_in[5];
  const void* b_dt    = d_in[6];
  const void* a_log   = d_in[7];
  const void* d_skip  = d_in[8];
  const void* w_out   = d_in[9];
  const void* ln1_g   = d_in[10];
  const void* ln1_b   = d_in[11];
  const void* ln2_g   = d_in[12];
  const void* ln2_b   = d_in[13];
  const void* ffn_w1  = d_in[14];
  const void* ffn_b1  = d_in[15];
  const void* ffn_w2  = d_in[16];
  const void* ffn_b2  = d_in[17];
  char* ws = (char*)d_ws;

  // ---- workspace layout (high-water ~127 MB) ----
  const size_t o_flag  = 0;
  const size_t o_small = 256;
  const size_t o_cwout = o_small + 65536;
  const size_t o_cff1  = o_cwout + (size_t)DM * DI * 2;
  const size_t o_cff2  = o_cff1  + (size_t)DM * DM * 2;
  const size_t o_cxp   = o_cff2  + (size_t)DM * DM * 2;
  const size_t o_cwdt  = o_cxp   + (size_t)NXP * DI * 2;
  const size_t o_xn    = 9437184;                         // 16 MiB region
  const size_t o_xp    = o_xn + (size_t)NTOK * DM * 2;    // 32 MiB
  const size_t o_z     = o_xp + (size_t)NTOK * DI * 2;    // 32 MiB
  const size_t o_u     = o_z  + (size_t)NTOK * DI * 2;    // 32 MiB
  const size_t o_bc    = o_u  + (size_t)NTOK * DI * 2;    // 128 KiB
  // scan state overlays the xn region (dead during the scan):
  const size_t SCN = (size_t)NCHK * NCH * 4;              // 2 MiB each
  const size_t o_S   = o_xn + 0 * SCN;
  const size_t o_hf0 = o_xn + 1 * SCN;
  const size_t o_hf1 = o_xn + 2 * SCN;
  const size_t o_hi0 = o_xn + 3 * SCN;
  const size_t o_hi1 = o_xn + 4 * SCN;                    // ends +10 MiB < 16 MiB

  int*   flagp   = (int*)(ws + o_flag);
  u16*   csmall  = (u16*)(ws + o_small);
  u16*   c_cwT   = csmall +     0;       // transposed conv weights [4][DI]
  u16*   c_convb = csmall +  8192;
  u16*   c_bdt   = csmall + 10240;
  u16*   c_alog  = csmall + 12288;
  u16*   c_dskip = csmall + 16384;
  u16*   c_ln1g  = csmall + 18432;
  u16*   c_ln1b  = csmall + 19456;
  u16*   c_ln2g  = csmall + 20480;
  u16*   c_ln2b  = csmall + 21504;
  u16*   c_fb1   = csmall + 22528;
  u16*   c_fb2   = csmall + 23552;
  u16*   c_wout  = (u16*)(ws + o_cwout);
  u16*   c_ff1   = (u16*)(ws + o_cff1);
  u16*   c_ff2   = (u16*)(ws + o_cff2);
  u16*   c_xproj = (u16*)(ws + o_cxp);
  u16*   c_wdt   = (u16*)(ws + o_cwdt);
  u16*   c_win   = (u16*)(ws + o_u);     // overlays u (dead until conv)
  u16*   xn      = (u16*)(ws + o_xn);
  u16*   xp      = (u16*)(ws + o_xp);
  u16*   zb      = (u16*)(ws + o_z);
  u16*   u       = (u16*)(ws + o_u);
  float* part    = (float*)(ws + o_xp);  // overlays xp (dead after conv)
  u16*   dtraw   = (u16*)(ws + o_xn);    // overlays xn (dead after in_proj)
  u16*   dtb     = xp;                   // overlays part (dead after reduce)
  u16*   yb      = xp;
  float* bc      = (float*)(ws + o_bc);
  float* S       = (float*)(ws + o_S);   // scan arrays overlay xn region;
  float* hf0     = (float*)(ws + o_hf0); // dtraw (first 1 MB) is consumed by
  float* hf1     = (float*)(ws + o_hf1); // the dt-GEMM before pass1 writes S
  float* hi0     = (float*)(ws + o_hi0);
  float* hi1     = (float*)(ws + o_hi1);
  float* h       = (float*)(ws + o_z);   // overlays z (dead after pass3)
  u16*   hn      = (u16*)(ws + o_xn);    // overlays scan arrays (dead)
  u16*   f1      = (u16*)(ws + o_u);     // overlays u (dead)

  const dim3 blk(256);

  // 0) detect dtype; weight copies are no-ops when inputs are already bf16
  detect_kernel<<<1, blk, 0, stream>>>((const u16*)x, flagp);
  convert_big<<<4228, blk, 0, stream>>>(
      (const float*)w_in, (const float*)w_xproj, (const float*)w_dt,
      (const float*)w_out, (const float*)ffn_w1, (const float*)ffn_w2,
      c_win, c_xproj, c_wdt, c_wout, c_ff1, c_ff2, flagp);
  convert_small_kernel<<<96, blk, 0, stream>>>(conv_w, conv_b, b_dt, a_log, d_skip,
                                               ln1_g, ln1_b, ln2_g, ln2_b, ffn_b1, ffn_b2,
                                               csmall, flagp);

  // 1) LN1(x) -> xn
  ln_kernel<true><<<NTOK / 2, blk, 0, stream>>>(x, c_ln1g, c_ln1b, xn, flagp);
  // 2) fused in_proj: [xp | z] = xn @ w_in^T   (N=4096 -> LNBX=5, 2048 blocks)
  gemm_kernel<6, 5><<<2048, blk, 0, stream>>>(xn, c_win, (const u16*)w_in,
                                              NTOK, 2 * DI, DM,
                                              nullptr, nullptr, nullptr, flagp, xp, zb);
  // 3) u = silu(conv(xp) + conv_b)
  conv_silu_kernel<<<NTOK, blk, 0, stream>>>(xp, c_cwT, c_convb, u);
  // 4) x_proj split-K (partials) + reduce -> dtraw (bf16), bc (f32)
  xproj_splitk<<<dim3(8, 64), blk, 0, stream>>>(u, c_xproj, (const u16*)w_xproj,
                                                flagp, part);
  xreduce_kernel<<<(NTOK * NXP + 255) / 256, blk, 0, stream>>>(part, dtraw, bc);
  // 5) dt = softplus(dtraw @ w_dt^T + b_dt)   (N=2048 -> LNBX=4, K=64 -> nk=2)
  gemm_kernel<2, 4><<<1024, blk, 0, stream>>>(dtraw, c_wdt, (const u16*)w_dt,
                                              NTOK, DI, DTR,
                                              c_bdt, nullptr, nullptr, flagp, dtb, nullptr);
  // 6) chunked scan -> yb = (y + d_skip*u) * silu(z)
  scan_pass1<<<NCHK * NCH / 4 / 256, blk, 0, stream>>>(dtb, u, bc, c_alog, S, hf0, hf1);
  scan_pass2<<<NCH / 256, blk, 0, stream>>>(S, hf0, hf1, c_alog, hi0, hi1);
  scan_pass3<<<NCHK * NCH / 4 / 256, blk, 0, stream>>>(dtb, u, bc, zb, c_alog, c_dskip,
                                                       hi0, hi1, yb);
  // 7) h = x + yb @ w_out^T   (N=1024 -> LNBX=3)
  gemm_kernel<3, 3><<<512, blk, 0, stream>>>(yb, c_wout, (const u16*)w_out,
                                             NTOK, DM, DI,
                                             nullptr, (const u16*)x, (const float*)x,
                                             flagp, h, nullptr);
  // 8) LN2(h) -> hn
  ln_kernel<false><<<NTOK / 2, blk, 0, stream>>>(h, c_ln2g, c_ln2b, hn, flagp);
  // 9) f1 = relu(hn @ ffn_w1^T + b1)
  gemm_kernel<4, 3><<<512, blk, 0, stream>>>(hn, c_ff1, (const u16*)ffn_w1,
                                             NTOK, DM, DM,
                                             c_fb1, nullptr, nullptr, flagp, f1, nullptr);
  // 10) out = h + f1 @ ffn_w2^T + b2
  gemm_kernel<5, 3><<<512, blk, 0, stream>>>(f1, c_ff2, (const u16*)ffn_w2,
                                             NTOK, DM, DM,
                                             c_fb2, nullptr, h, flagp, d_out, nullptr);
}

// Round 8
// 488.526 us; speedup vs baseline: 1.9775x; 1.9775x over previous
//
#include <hip/hip_runtime.h>

typedef unsigned short u16;
typedef __bf16 bf16x8 __attribute__((ext_vector_type(8)));
typedef float f32x4 __attribute__((ext_vector_type(4)));
typedef float f32x2 __attribute__((ext_vector_type(2)));
typedef u16 u16x4 __attribute__((ext_vector_type(4)));
typedef u16 u16x8 __attribute__((ext_vector_type(8)));

// Problem constants
#define SEQ   4096
#define DM    1024
#define DI    2048
#define NTOK  8192      // BATCH * SEQ
#define NXP   68        // DT_RANK + 2*D_STATE
#define DTR   64        // DT_RANK
#define NCH   4096      // BATCH * DI channels for scan
#define CHUNK 32
#define NCHK  128       // SEQ / CHUNK

__device__ __forceinline__ float bf2f(u16 v) {
  union { unsigned u; float f; } x; x.u = ((unsigned)v) << 16; return x.f;
}
__device__ __forceinline__ u16 f2bf(float f) {
  unsigned u = __float_as_uint(f);
  return (u16)((u + 0x7FFFu + ((u >> 16) & 1u)) >> 16);   // RNE
}

// async global->LDS DMA, 16B/lane; LDS dest = wave-uniform base + lane*16
__device__ __forceinline__ void g2l16(const u16* g, u16* l) {
  __builtin_amdgcn_global_load_lds(
      (const __attribute__((address_space(1))) unsigned int*)g,
      (__attribute__((address_space(3))) unsigned int*)l, 16, 0, 0);
}

// ---------------------------------------------------------------------------
// Input dtype detection (f32 inputs -> low u16 has huge bf16 exponents)
// ---------------------------------------------------------------------------
__global__ __launch_bounds__(256)
void detect_kernel(const u16* __restrict__ x, int* __restrict__ flag)
{
  __shared__ int tot;
  if (threadIdx.x == 0) tot = 0;
  __syncthreads();
  int cnt = 0;
  for (int i = threadIdx.x; i < 4096; i += 256) {
    const int e = (x[2 * i] >> 7) & 0xFF;
    if (e > 167) cnt++;
  }
  atomicAdd(&tot, cnt);
  __syncthreads();
  if (threadIdx.x == 0) flag[0] = (tot >= 8) ? 1 : 0;
}

// ---------------------------------------------------------------------------
// ONE conversion launch. Blocks < NBB: 6 big weights, 8 elems/thread (no-op
// when inputs are bf16). Blocks >= NBB: 11 small vectors incl. conv_w
// transpose to [4][DI] (always runs).
// ---------------------------------------------------------------------------
#define NW0 4194304   // w_in
#define NW1  139264   // w_xproj
#define NW2  131072   // w_dt
#define NW3 2097152   // w_out
#define NW4 1048576   // ffn_w1
#define NW5 1048576   // ffn_w2
#define NBB 4228      // ceil((sum NW)/8/256)
__global__ __launch_bounds__(256)
void convert_all(const float* __restrict__ s0, const float* __restrict__ s1,
                 const float* __restrict__ s2, const float* __restrict__ s3,
                 const float* __restrict__ s4, const float* __restrict__ s5,
                 u16* __restrict__ d0, u16* __restrict__ d1, u16* __restrict__ d2,
                 u16* __restrict__ d3, u16* __restrict__ d4, u16* __restrict__ d5,
                 const void* t0, const void* t1, const void* t2, const void* t3,
                 const void* t4, const void* t5, const void* t6, const void* t7,
                 const void* t8, const void* t9, const void* t10,
                 u16* __restrict__ dsm, const int* __restrict__ flag)
{
  if (blockIdx.x >= NBB) {
    const int i = (blockIdx.x - NBB) * 256 + threadIdx.x;
    if (i >= 24576) return;
    const void* src; int off; int dsti = i;
    if      (i < 8192)  { src = t0;  off = i;
                          dsti = (off & 3) * DI + (off >> 2); }  // conv_w -> [j][d]
    else if (i < 10240) { src = t1;  off = i - 8192; }   // conv_b
    else if (i < 12288) { src = t2;  off = i - 10240; }  // b_dt
    else if (i < 16384) { src = t3;  off = i - 12288; }  // a_log
    else if (i < 18432) { src = t4;  off = i - 16384; }  // d_skip
    else if (i < 19456) { src = t5;  off = i - 18432; }  // ln1_g
    else if (i < 20480) { src = t6;  off = i - 19456; }  // ln1_b
    else if (i < 21504) { src = t7;  off = i - 20480; }  // ln2_g
    else if (i < 22528) { src = t8;  off = i - 21504; }  // ln2_b
    else if (i < 23552) { src = t9;  off = i - 22528; }  // ffn_b1
    else                { src = t10; off = i - 23552; }  // ffn_b2
    dsm[dsti] = (*flag) ? f2bf(((const float*)src)[off]) : ((const u16*)src)[off];
    return;
  }
  if (*flag == 0) return;
  long e = ((long)blockIdx.x * 256 + threadIdx.x) * 8;
  const long c1 = NW0, c2 = c1 + NW1, c3 = c2 + NW2, c4 = c3 + NW3,
             c5 = c4 + NW4, c6 = c5 + NW5;
  if (e >= c6) return;
  const float* s; u16* d;
  if      (e < c1) { s = s0;          d = d0; }
  else if (e < c2) { s = s1; e -= c1; d = d1; }
  else if (e < c3) { s = s2; e -= c2; d = d2; }
  else if (e < c4) { s = s3; e -= c3; d = d3; }
  else if (e < c5) { s = s4; e -= c4; d = d4; }
  else             { s = s5; e -= c5; d = d5; }
  f32x4 a = *(const f32x4*)(s + e);
  f32x4 b = *(const f32x4*)(s + e + 4);
  u16x8 o;
#pragma unroll
  for (int k = 0; k < 4; ++k) { o[k] = f2bf(a[k]); o[4 + k] = f2bf(b[k]); }
  *(u16x8*)(d + e) = o;
}

// ---------------------------------------------------------------------------
// LayerNorm: 2 rows per block, 8 elems per thread, vectorized loads/stores.
// ---------------------------------------------------------------------------
template<bool DUAL>
__global__ __launch_bounds__(256)
void ln_kernel(const void* __restrict__ xin, const u16* __restrict__ gw,
               const u16* __restrict__ bw, u16* __restrict__ outp,
               const int* __restrict__ flag)
{
  const int tid = threadIdx.x;
  const int sub = tid >> 7;                  // row within block
  const int col0 = (tid & 127) * 8;
  const int row = blockIdx.x * 2 + sub;
  const bool isf32 = DUAL ? (*flag != 0) : true;
  float v[8];
  if (isf32) {
    const float* xf = (const float*)xin + (size_t)row * DM + col0;
    f32x4 a = *(const f32x4*)xf, b2 = *(const f32x4*)(xf + 4);
#pragma unroll
    for (int k = 0; k < 4; ++k) { v[k] = a[k]; v[4 + k] = b2[k]; }
  } else {
    u16x8 xb = *(const u16x8*)((const u16*)xin + (size_t)row * DM + col0);
#pragma unroll
    for (int k = 0; k < 8; ++k) v[k] = bf2f(xb[k]);
  }
  float s = 0.f, s2 = 0.f;
#pragma unroll
  for (int k = 0; k < 8; ++k) { s += v[k]; s2 += v[k] * v[k]; }
#pragma unroll
  for (int off = 32; off > 0; off >>= 1) {
    s  += __shfl_down(s,  off);
    s2 += __shfl_down(s2, off);
  }
  __shared__ float red[4], red2[4];
  __shared__ f32x2 stat[2];
  const int wv = tid >> 6;
  if ((tid & 63) == 0) { red[wv] = s; red2[wv] = s2; }
  __syncthreads();
  if ((tid & 127) == 0) {
    float ts = red[sub * 2] + red[sub * 2 + 1];
    float t2 = red2[sub * 2] + red2[sub * 2 + 1];
    float mu = ts * (1.f / DM);
    float var = t2 * (1.f / DM) - mu * mu;
    stat[sub] = f32x2{mu, rsqrtf(var + 1e-5f)};
  }
  __syncthreads();
  const float mu = stat[sub][0], rs = stat[sub][1];
  u16x8 gv = *(const u16x8*)(gw + col0), bv = *(const u16x8*)(bw + col0);
  u16x8 o;
#pragma unroll
  for (int k = 0; k < 8; ++k)
    o[k] = f2bf((v[k] - mu) * rs * bf2f(gv[k]) + bf2f(bv[k]));
  *(u16x8*)(outp + (size_t)row * DM + col0) = o;
}

// ---------------------------------------------------------------------------
// bf16 MFMA GEMM (round-6 proven version): C[M,N] = A[M,K] @ B[N,K]^T.
// 128x128 tile, BK=32, double-buffered LDS, global_load_lds(16B) prefetch,
// one barrier/iter, XCD swizzle, XOR bank-swizzle on fetch-side lane->chunk
// (LDS reads conflict-free with q^rsw).
// Requires: M%128==0, N%128==0, K%32==0, gridDim.x == (N/128)*64, N/128==1<<LNBX.
// EPI: 1 bf16 | 2 +bias,softplus->bf16 | 3 +x(flag dtype)->f32 |
//      4 +bias,relu->bf16 | 5 +bias+addf32 -> out(bf16/f32 per flag) |
//      6 split store: col<DI -> Cp (bf16), else -> Cp2 (bf16), row stride DI
// ---------------------------------------------------------------------------
template<int EPI, int LNBX>
__global__ __launch_bounds__(256, 2)
void gemm_kernel(const u16* __restrict__ A, const u16* __restrict__ Bc,
                 const u16* __restrict__ Braw,
                 int M, int N, int K,
                 const u16* __restrict__ bias, const u16* __restrict__ addbf,
                 const float* __restrict__ addf, const int* __restrict__ dtflag,
                 void* __restrict__ Cp, void* __restrict__ Cp2)
{
  __shared__ __align__(16) u16 sA[2][128 * 32];
  __shared__ __align__(16) u16 sB[2][128 * 32];
  const int fl = *dtflag;
  const u16* __restrict__ B = fl ? Bc : Braw;
  const int tid = threadIdx.x;
  const int b = blockIdx.x;
  const int xcd = b & 7;
  const int kk = b >> 3;
  const int bx = kk & ((1 << LNBX) - 1);
  const int by = xcd * 8 + (kk >> LNBX);
  const int m0 = by * 128;
  const int n0 = bx * 128;
  const int lane = tid & 63;
  const int wv = tid >> 6;
  const int wm = (wv & 1) * 64;
  const int wn = (wv >> 1) * 64;
  const int r = lane & 15;
  const int q = lane >> 4;
  const int rsw = (r >> 1) & 3;        // read-side bank swizzle

  const int pr = lane >> 2;            // 0..15 row in 16-row staging chunk
  const int kc = (lane & 3) ^ ((pr >> 1) & 3);   // swizzled source k-chunk
  const int pk = kc * 8;
  u16* lA0[2] = { &sA[0][(wv * 2 + 0) * 512], &sA[1][(wv * 2 + 0) * 512] };
  u16* lA1[2] = { &sA[0][(wv * 2 + 1) * 512], &sA[1][(wv * 2 + 1) * 512] };
  u16* lB0[2] = { &sB[0][(wv * 2 + 0) * 512], &sB[1][(wv * 2 + 0) * 512] };
  u16* lB1[2] = { &sB[0][(wv * 2 + 1) * 512], &sB[1][(wv * 2 + 1) * 512] };
  const u16* gA0 = A + (size_t)(m0 + wv * 32 + pr) * K + pk;
  const u16* gA1 = gA0 + (size_t)16 * K;
  const u16* gB0 = B + (size_t)(n0 + wv * 32 + pr) * K + pk;
  const u16* gB1 = gB0 + (size_t)16 * K;

  f32x4 acc[4][4];
#pragma unroll
  for (int i = 0; i < 4; ++i)
#pragma unroll
    for (int j = 0; j < 4; ++j)
#pragma unroll
      for (int t = 0; t < 4; ++t) acc[i][j][t] = 0.f;

  g2l16(gA0, lA0[0]); g2l16(gA1, lA1[0]);
  g2l16(gB0, lB0[0]); g2l16(gB1, lB1[0]);

  const int nk = K >> 5;
  for (int kt = 0; kt < nk; ++kt) {
    const int cur = kt & 1;
    __syncthreads();   // drains vmcnt(0): tile-kt deposits complete
    bf16x8 af[4], bfr[4];
#pragma unroll
    for (int i = 0; i < 4; ++i)
      af[i] = *reinterpret_cast<const bf16x8*>(
          &sA[cur][(wm + i * 16 + r) * 32 + (q ^ rsw) * 8]);
#pragma unroll
    for (int j = 0; j < 4; ++j)
      bfr[j] = *reinterpret_cast<const bf16x8*>(
          &sB[cur][(wn + j * 16 + r) * 32 + (q ^ rsw) * 8]);
    if (kt + 1 < nk) {
      gA0 += 32; gA1 += 32; gB0 += 32; gB1 += 32;
      g2l16(gA0, lA0[cur ^ 1]); g2l16(gA1, lA1[cur ^ 1]);
      g2l16(gB0, lB0[cur ^ 1]); g2l16(gB1, lB1[cur ^ 1]);
    }
#pragma unroll
    for (int i = 0; i < 4; ++i)
#pragma unroll
      for (int j = 0; j < 4; ++j)
        acc[i][j] = __builtin_amdgcn_mfma_f32_16x16x32_bf16(af[i], bfr[j], acc[i][j], 0, 0, 0);
  }

  // epilogue: D row = wm+i*16+q*4+t (M), col = wn+j*16+r (N)
#pragma unroll
  for (int i = 0; i < 4; ++i) {
#pragma unroll
    for (int j = 0; j < 4; ++j) {
#pragma unroll
      for (int t = 0; t < 4; ++t) {
        const int row = m0 + wm + i * 16 + q * 4 + t;
        const int col = n0 + wn + j * 16 + r;
        float v = acc[i][j][t];
        if (EPI == 6) {
          const size_t rb = (size_t)row * DI;
          if (col < DI) ((u16*)Cp)[rb + col] = f2bf(v);
          else          ((u16*)Cp2)[rb + col - DI] = f2bf(v);
        } else {
          const size_t idx = (size_t)row * N + col;
          if (EPI == 1) {
            ((u16*)Cp)[idx] = f2bf(v);
          } else if (EPI == 2) {           // dt = softplus(v + b_dt)
            v += bf2f(bias[col]);
            v = (v > 15.f) ? v : __logf(1.f + __expf(v));
            ((u16*)Cp)[idx] = f2bf(v);
          } else if (EPI == 3) {           // h = x + mamba_out (f32)
            v += fl ? addf[idx] : bf2f(addbf[idx]);
            ((float*)Cp)[idx] = v;
          } else if (EPI == 4) {           // relu(v + b1)
            v += bf2f(bias[col]);
            ((u16*)Cp)[idx] = f2bf(fmaxf(v, 0.f));
          } else {                         // out = h + v + b2
            v += bf2f(bias[col]) + addf[idx];
            if (fl) ((float*)Cp)[idx] = v;
            else    ((u16*)Cp)[idx] = f2bf(v);
          }
        }
      }
    }
  }
}

// ---------------------------------------------------------------------------
// x_proj split-K: part[z] = u[:, z*256:(z+1)*256] @ w_xproj[:, same]^T
// grid (8, 64). Output f32 partials [8, NTOK, 68]. Round-6 dbuf pipeline.
// ---------------------------------------------------------------------------
__global__ __launch_bounds__(256, 2)
void xproj_splitk(const u16* __restrict__ A, const u16* __restrict__ Bc,
                  const u16* __restrict__ Braw, const int* __restrict__ dtflag,
                  float* __restrict__ part)
{
  __shared__ __align__(16) u16 sA[2][128 * 32];
  __shared__ __align__(16) u16 sB[2][128 * 32];
  const int fl = *dtflag;
  const u16* __restrict__ B = fl ? Bc : Braw;
  const int tid = threadIdx.x;
  const int kz = blockIdx.x;           // 0..7
  const int m0 = blockIdx.y * 128;
  const int kbase = kz * 256;
  const int lane = tid & 63;
  const int wv = tid >> 6;
  const int wm = (wv & 1) * 64;
  const int wn = (wv >> 1) * 64;
  const int r = lane & 15;
  const int q = lane >> 4;
  const int rsw = (r >> 1) & 3;
  const int pr = lane >> 2;
  const int kc = (lane & 3) ^ ((pr >> 1) & 3);
  const int pk = kc * 8;

  u16* lA0[2] = { &sA[0][(wv * 2 + 0) * 512], &sA[1][(wv * 2 + 0) * 512] };
  u16* lA1[2] = { &sA[0][(wv * 2 + 1) * 512], &sA[1][(wv * 2 + 1) * 512] };
  u16* lB0[2] = { &sB[0][(wv * 2 + 0) * 512], &sB[1][(wv * 2 + 0) * 512] };
  u16* lB1[2] = { &sB[0][(wv * 2 + 1) * 512], &sB[1][(wv * 2 + 1) * 512] };
  int br0 = wv * 32 + pr;      if (br0 > 67) br0 = 67;   // junk cols unused
  int br1 = wv * 32 + 16 + pr; if (br1 > 67) br1 = 67;
  const u16* gA0 = A + (size_t)(m0 + wv * 32 + pr) * DI + kbase + pk;
  const u16* gA1 = gA0 + (size_t)16 * DI;
  const u16* gB0 = B + (size_t)br0 * DI + kbase + pk;
  const u16* gB1 = B + (size_t)br1 * DI + kbase + pk;

  f32x4 acc[4][4];
#pragma unroll
  for (int i = 0; i < 4; ++i)
#pragma unroll
    for (int j = 0; j < 4; ++j)
#pragma unroll
      for (int t = 0; t < 4; ++t) acc[i][j][t] = 0.f;

  g2l16(gA0, lA0[0]); g2l16(gA1, lA1[0]);
  g2l16(gB0, lB0[0]); g2l16(gB1, lB1[0]);

  for (int kt = 0; kt < 8; ++kt) {
    const int cur = kt & 1;
    __syncthreads();
    bf16x8 af[4], bfr[4];
#pragma unroll
    for (int i = 0; i < 4; ++i)
      af[i] = *reinterpret_cast<const bf16x8*>(
          &sA[cur][(wm + i * 16 + r) * 32 + (q ^ rsw) * 8]);
#pragma unroll
    for (int j = 0; j < 4; ++j)
      bfr[j] = *reinterpret_cast<const bf16x8*>(
          &sB[cur][(wn + j * 16 + r) * 32 + (q ^ rsw) * 8]);
    if (kt + 1 < 8) {
      gA0 += 32; gA1 += 32; gB0 += 32; gB1 += 32;
      g2l16(gA0, lA0[cur ^ 1]); g2l16(gA1, lA1[cur ^ 1]);
      g2l16(gB0, lB0[cur ^ 1]); g2l16(gB1, lB1[cur ^ 1]);
    }
#pragma unroll
    for (int i = 0; i < 4; ++i)
#pragma unroll
      for (int j = 0; j < 4; ++j)
        acc[i][j] = __builtin_amdgcn_mfma_f32_16x16x32_bf16(af[i], bfr[j], acc[i][j], 0, 0, 0);
  }

#pragma unroll
  for (int i = 0; i < 4; ++i)
#pragma unroll
    for (int j = 0; j < 4; ++j)
#pragma unroll
      for (int t = 0; t < 4; ++t) {
        const int row = m0 + wm + i * 16 + q * 4 + t;
        const int col = wn + j * 16 + r;
        if (col < NXP)
          part[((size_t)kz * NTOK + row) * NXP + col] = acc[i][j][t];
      }
}

// Reduce partials: cols 0..63 -> dtraw bf16 [NTOK,64]; 64..67 -> bc f32 [NTOK,4]
__global__ __launch_bounds__(256)
void xreduce_kernel(const float* __restrict__ part, u16* __restrict__ dtraw,
                    float* __restrict__ bc)
{
  const int i = blockIdx.x * 256 + threadIdx.x;
  if (i >= NTOK * NXP) return;
  const int row = i / NXP, col = i - row * NXP;
  float s = 0.f;
#pragma unroll
  for (int z = 0; z < 8; ++z) s += part[(size_t)z * NTOK * NXP + i];
  if (col < DTR) dtraw[(size_t)row * DTR + col] = f2bf(s);
  else           bc[row * 4 + (col - DTR)] = s;
}

// ---------------------------------------------------------------------------
// Depthwise causal conv (k=4, transposed weights) + bias + SiLU, x8 vectorized.
// ---------------------------------------------------------------------------
__global__ __launch_bounds__(256)
void conv_silu_kernel(const u16* __restrict__ xp, const u16* __restrict__ cwT,
                      const u16* __restrict__ cb, u16* __restrict__ u)
{
  const int token = blockIdx.x;
  const int t = token & (SEQ - 1);
  const int d0 = threadIdx.x * 8;
  const ptrdiff_t base = (ptrdiff_t)token * DI + d0;
  float acc[8];
  u16x8 cbv = *(const u16x8*)(cb + d0);
#pragma unroll
  for (int k = 0; k < 8; ++k) acc[k] = bf2f(cbv[k]);
#pragma unroll
  for (int j = 0; j < 4; ++j) {
    if (t - 3 + j >= 0) {
      u16x8 xv = *(const u16x8*)(xp + base + (ptrdiff_t)(j - 3) * DI);
      u16x8 wv = *(const u16x8*)(cwT + j * DI + d0);
#pragma unroll
      for (int k = 0; k < 8; ++k) acc[k] += bf2f(wv[k]) * bf2f(xv[k]);
    }
  }
  u16x8 o;
#pragma unroll
  for (int k = 0; k < 8; ++k) {
    const float sg = 1.f / (1.f + __expf(-acc[k]));
    o[k] = f2bf(acc[k] * sg);
  }
  *(u16x8*)(u + base) = o;
}

// ---------------------------------------------------------------------------
// Chunked SSM scan (N=2 states), 4 channels per thread, CHUNK=32.
// ---------------------------------------------------------------------------
__global__ __launch_bounds__(256)
void scan_pass1(const u16* __restrict__ dtb, const u16* __restrict__ ub,
                const float* __restrict__ bc, const u16* __restrict__ a_log,
                float* __restrict__ S, float* __restrict__ hf0, float* __restrict__ hf1)
{
  const int g4 = blockIdx.x * 256 + threadIdx.x;   // NCHK*NCH/4
  const int chg = g4 & (NCH / 4 - 1);
  const int c = g4 >> 10;
  const int ch0 = chg * 4;
  const int b = ch0 >> 11;
  const int d0 = ch0 & (DI - 1);
  u16x8 av = *(const u16x8*)(a_log + d0 * 2);
  float A0[4], A1[4];
#pragma unroll
  for (int k = 0; k < 4; ++k) {
    A0[k] = -__expf(bf2f(av[2 * k]));
    A1[k] = -__expf(bf2f(av[2 * k + 1]));
  }
  float h0[4] = {0.f, 0.f, 0.f, 0.f}, h1[4] = {0.f, 0.f, 0.f, 0.f};
  float s[4] = {0.f, 0.f, 0.f, 0.f};
  const int row0 = b * SEQ + c * CHUNK;
  for (int i = 0; i < CHUNK; ++i) {
    const size_t row = row0 + i;
    u16x4 dtv = *(const u16x4*)(dtb + row * DI + d0);
    u16x4 uv  = *(const u16x4*)(ub + row * DI + d0);
    f32x2 Bv = *(const f32x2*)(bc + row * 4);
#pragma unroll
    for (int k = 0; k < 4; ++k) {
      const float dt = bf2f(dtv[k]);
      const float dtu = dt * bf2f(uv[k]);
      h0[k] = __expf(A0[k] * dt) * h0[k] + dtu * Bv[0];
      h1[k] = __expf(A1[k] * dt) * h1[k] + dtu * Bv[1];
      s[k] += dt;
    }
  }
  const size_t g0 = (size_t)c * NCH + ch0;
  *(f32x4*)(S + g0)   = f32x4{s[0], s[1], s[2], s[3]};
  *(f32x4*)(hf0 + g0) = f32x4{h0[0], h0[1], h0[2], h0[3]};
  *(f32x4*)(hf1 + g0) = f32x4{h1[0], h1[1], h1[2], h1[3]};
}

__global__ __launch_bounds__(256)
void scan_pass2(const float* __restrict__ S, const float* __restrict__ hf0,
                const float* __restrict__ hf1, const u16* __restrict__ a_log,
                float* __restrict__ hi0, float* __restrict__ hi1)
{
  const int ch = blockIdx.x * 256 + threadIdx.x;  // NCH
  const int d = ch & (DI - 1);
  const float A0 = -__expf(bf2f(a_log[d * 2 + 0]));
  const float A1 = -__expf(bf2f(a_log[d * 2 + 1]));
  float h0 = 0.f, h1 = 0.f;
  // software-pipelined: prefetch next chunk's state while combining current
  size_t g = ch;
  float sv = S[g], f0 = hf0[g], f1 = hf1[g];
  for (int c = 0; c < NCHK; ++c) {
    float svn = 0.f, f0n = 0.f, f1n = 0.f;
    if (c + 1 < NCHK) {
      const size_t gn = g + NCH;
      svn = S[gn]; f0n = hf0[gn]; f1n = hf1[gn];
    }
    hi0[g] = h0; hi1[g] = h1;
    h0 = __expf(A0 * sv) * h0 + f0;
    h1 = __expf(A1 * sv) * h1 + f1;
    sv = svn; f0 = f0n; f1 = f1n;
    g += NCH;
  }
}

__global__ __launch_bounds__(256)
void scan_pass3(const u16* __restrict__ dtb, const u16* __restrict__ ub,
                const float* __restrict__ bc, const u16* __restrict__ zbuf,
                const u16* __restrict__ a_log, const u16* __restrict__ d_skip,
                const float* __restrict__ hi0, const float* __restrict__ hi1,
                u16* __restrict__ yb)
{
  const int g4 = blockIdx.x * 256 + threadIdx.x;
  const int chg = g4 & (NCH / 4 - 1);
  const int c = g4 >> 10;
  const int ch0 = chg * 4;
  const int b = ch0 >> 11;
  const int d0 = ch0 & (DI - 1);
  u16x8 av = *(const u16x8*)(a_log + d0 * 2);
  u16x4 dkv = *(const u16x4*)(d_skip + d0);
  float A0[4], A1[4], dsk[4];
#pragma unroll
  for (int k = 0; k < 4; ++k) {
    A0[k] = -__expf(bf2f(av[2 * k]));
    A1[k] = -__expf(bf2f(av[2 * k + 1]));
    dsk[k] = bf2f(dkv[k]);
  }
  const size_t g0 = (size_t)c * NCH + ch0;
  f32x4 h0v = *(const f32x4*)(hi0 + g0);
  f32x4 h1v = *(const f32x4*)(hi1 + g0);
  float h0[4], h1[4];
#pragma unroll
  for (int k = 0; k < 4; ++k) { h0[k] = h0v[k]; h1[k] = h1v[k]; }
  const int row0 = b * SEQ + c * CHUNK;
  for (int i = 0; i < CHUNK; ++i) {
    const size_t row = row0 + i;
    u16x4 dtv = *(const u16x4*)(dtb + row * DI + d0);
    u16x4 uv  = *(const u16x4*)(ub + row * DI + d0);
    u16x4 zv  = *(const u16x4*)(zbuf + row * DI + d0);
    f32x4 bcv = *(const f32x4*)(bc + row * 4);
    u16x4 o;
#pragma unroll
    for (int k = 0; k < 4; ++k) {
      const float dt = bf2f(dtv[k]);
      const float uu = bf2f(uv[k]);
      const float dtu = dt * uu;
      h0[k] = __expf(A0[k] * dt) * h0[k] + dtu * bcv[0];
      h1[k] = __expf(A1[k] * dt) * h1[k] + dtu * bcv[1];
      const float y = h0[k] * bcv[2] + h1[k] * bcv[3];
      const float z = bf2f(zv[k]);
      const float sz = z / (1.f + __expf(-z));
      o[k] = f2bf((y + dsk[k] * uu) * sz);
    }
    *(u16x4*)(yb + row * DI + d0) = o;    // in-place over dtb: ok
  }
}

// ---------------------------------------------------------------------------
extern "C" void kernel_launch(void* const* d_in, const int* in_sizes, int n_in,
                              void* d_out, int out_size, void* d_ws, size_t ws_size,
                              hipStream_t stream)
{
  const void* x       = d_in[0];
  const void* w_in    = d_in[1];
  const void* conv_w  = d_in[2];
  const void* conv_b  = d_in[3];
  const void* w_xproj = d_in[4];
  const void* w_dt    = d_in[5];
  const void* b_dt    = d_in[6];
  const void* a_log   = d_in[7];
  const void* d_skip  = d_in[8];
  const void* w_out   = d_in[9];
  const void* ln1_g   = d_in[10];
  const void* ln1_b   = d_in[11];
  const void* ln2_g   = d_in[12];
  const void* ln2_b   = d_in[13];
  const void* ffn_w1  = d_in[14];
  const void* ffn_b1  = d_in[15];
  const void* ffn_w2  = d_in[16];
  const void* ffn_b2  = d_in[17];
  char* ws = (char*)d_ws;

  // ---- workspace layout (high-water ~127 MB) ----
  const size_t o_flag  = 0;
  const size_t o_small = 256;
  const size_t o_cwout = o_small + 65536;
  const size_t o_cff1  = o_cwout + (size_t)DM * DI * 2;
  const size_t o_cff2  = o_cff1  + (size_t)DM * DM * 2;
  const size_t o_cxp   = o_cff2  + (size_t)DM * DM * 2;
  const size_t o_cwdt  = o_cxp   + (size_t)NXP * DI * 2;
  const size_t o_xn    = 9437184;                         // 16 MiB region
  const size_t o_xp    = o_xn + (size_t)NTOK * DM * 2;    // 32 MiB
  const size_t o_z     = o_xp + (size_t)NTOK * DI * 2;    // 32 MiB
  const size_t o_u     = o_z  + (size_t)NTOK * DI * 2;    // 32 MiB
  const size_t o_bc    = o_u  + (size_t)NTOK * DI * 2;    // 128 KiB
  // scan state overlays the xn region (dead during the scan):
  const size_t SCN = (size_t)NCHK * NCH * 4;              // 2 MiB each
  const size_t o_S   = o_xn + 0 * SCN;
  const size_t o_hf0 = o_xn + 1 * SCN;
  const size_t o_hf1 = o_xn + 2 * SCN;
  const size_t o_hi0 = o_xn + 3 * SCN;
  const size_t o_hi1 = o_xn + 4 * SCN;                    // ends +10 MiB < 16 MiB

  int*   flagp   = (int*)(ws + o_flag);
  u16*   csmall  = (u16*)(ws + o_small);
  u16*   c_cwT   = csmall +     0;       // transposed conv weights [4][DI]
  u16*   c_convb = csmall +  8192;
  u16*   c_bdt   = csmall + 10240;
  u16*   c_alog  = csmall + 12288;
  u16*   c_dskip = csmall + 16384;
  u16*   c_ln1g  = csmall + 18432;
  u16*   c_ln1b  = csmall + 19456;
  u16*   c_ln2g  = csmall + 20480;
  u16*   c_ln2b  = csmall + 21504;
  u16*   c_fb1   = csmall + 22528;
  u16*   c_fb2   = csmall + 23552;
  u16*   c_wout  = (u16*)(ws + o_cwout);
  u16*   c_ff1   = (u16*)(ws + o_cff1);
  u16*   c_ff2   = (u16*)(ws + o_cff2);
  u16*   c_xproj = (u16*)(ws + o_cxp);
  u16*   c_wdt   = (u16*)(ws + o_cwdt);
  u16*   c_win   = (u16*)(ws + o_u);     // overlays u (dead until conv)
  u16*   xn      = (u16*)(ws + o_xn);
  u16*   xp      = (u16*)(ws + o_xp);
  u16*   zb      = (u16*)(ws + o_z);
  u16*   u       = (u16*)(ws + o_u);
  float* part    = (float*)(ws + o_xp);  // overlays xp (dead after conv)
  u16*   dtraw   = (u16*)(ws + o_xn);    // overlays xn (dead after in_proj)
  u16*   dtb     = xp;                   // overlays part (dead after reduce)
  u16*   yb      = xp;
  float* bc      = (float*)(ws + o_bc);
  float* S       = (float*)(ws + o_S);   // scan arrays overlay xn region;
  float* hf0     = (float*)(ws + o_hf0); // dtraw (first 1 MB) is consumed by
  float* hf1     = (float*)(ws + o_hf1); // the dt-GEMM before pass1 writes S
  float* hi0     = (float*)(ws + o_hi0);
  float* hi1     = (float*)(ws + o_hi1);
  float* h       = (float*)(ws + o_z);   // overlays z (dead after pass3)
  u16*   hn      = (u16*)(ws + o_xn);    // overlays scan arrays (dead)
  u16*   f1      = (u16*)(ws + o_u);     // overlays u (dead)

  const dim3 blk(256);

  // 0) detect dtype; all param conversion in ONE launch (no-op weights on bf16)
  detect_kernel<<<1, blk, 0, stream>>>((const u16*)x, flagp);
  convert_all<<<NBB + 96, blk, 0, stream>>>(
      (const float*)w_in, (const float*)w_xproj, (const float*)w_dt,
      (const float*)w_out, (const float*)ffn_w1, (const float*)ffn_w2,
      c_win, c_xproj, c_wdt, c_wout, c_ff1, c_ff2,
      conv_w, conv_b, b_dt, a_log, d_skip,
      ln1_g, ln1_b, ln2_g, ln2_b, ffn_b1, ffn_b2,
      csmall, flagp);

  // 1) LN1(x) -> xn
  ln_kernel<true><<<NTOK / 2, blk, 0, stream>>>(x, c_ln1g, c_ln1b, xn, flagp);
  // 2) fused in_proj: [xp | z] = xn @ w_in^T   (N=4096 -> LNBX=5, 2048 blocks)
  gemm_kernel<6, 5><<<2048, blk, 0, stream>>>(xn, c_win, (const u16*)w_in,
                                              NTOK, 2 * DI, DM,
                                              nullptr, nullptr, nullptr, flagp, xp, zb);
  // 3) u = silu(conv(xp) + conv_b)
  conv_silu_kernel<<<NTOK, blk, 0, stream>>>(xp, c_cwT, c_convb, u);
  // 4) x_proj split-K (partials) + reduce -> dtraw (bf16), bc (f32)
  xproj_splitk<<<dim3(8, 64), blk, 0, stream>>>(u, c_xproj, (const u16*)w_xproj,
                                                flagp, part);
  xreduce_kernel<<<(NTOK * NXP + 255) / 256, blk, 0, stream>>>(part, dtraw, bc);
  // 5) dt = softplus(dtraw @ w_dt^T + b_dt)   (N=2048 -> LNBX=4)
  gemm_kernel<2, 4><<<1024, blk, 0, stream>>>(dtraw, c_wdt, (const u16*)w_dt,
                                              NTOK, DI, DTR,
                                              c_bdt, nullptr, nullptr, flagp, dtb, nullptr);
  // 6) chunked scan -> yb = (y + d_skip*u) * silu(z)
  scan_pass1<<<NCHK * NCH / 4 / 256, blk, 0, stream>>>(dtb, u, bc, c_alog, S, hf0, hf1);
  scan_pass2<<<NCH / 256, blk, 0, stream>>>(S, hf0, hf1, c_alog, hi0, hi1);
  scan_pass3<<<NCHK * NCH / 4 / 256, blk, 0, stream>>>(dtb, u, bc, zb, c_alog, c_dskip,
                                                       hi0, hi1, yb);
  // 7) h = x + yb @ w_out^T   (N=1024 -> LNBX=3)
  gemm_kernel<3, 3><<<512, blk, 0, stream>>>(yb, c_wout, (const u16*)w_out,
                                             NTOK, DM, DI,
                                             nullptr, (const u16*)x, (const float*)x,
                                             flagp, h, nullptr);
  // 8) LN2(h) -> hn
  ln_kernel<false><<<NTOK / 2, blk, 0, stream>>>(h, c_ln2g, c_ln2b, hn, flagp);
  // 9) f1 = relu(hn @ ffn_w1^T + b1)
  gemm_kernel<4, 3><<<512, blk, 0, stream>>>(hn, c_ff1, (const u16*)ffn_w1,
                                             NTOK, DM, DM,
                                             c_fb1, nullptr, nullptr, flagp, f1, nullptr);
  // 10) out = h + f1 @ ffn_w2^T + b2
  gemm_kernel<5, 3><<<512, blk, 0, stream>>>(f1, c_ff2, (const u16*)ffn_w2,
                                             NTOK, DM, DM,
                                             c_fb2, nullptr, h, flagp, d_out, nullptr);
}

// Round 9
// 483.237 us; speedup vs baseline: 1.9991x; 1.0109x over previous
//
#include <hip/hip_runtime.h>

typedef unsigned short u16;
typedef __bf16 bf16x8 __attribute__((ext_vector_type(8)));
typedef float f32x4 __attribute__((ext_vector_type(4)));
typedef float f32x2 __attribute__((ext_vector_type(2)));
typedef u16 u16x4 __attribute__((ext_vector_type(4)));
typedef u16 u16x8 __attribute__((ext_vector_type(8)));

// Problem constants
#define SEQ   4096
#define DM    1024
#define DI    2048
#define NTOK  8192      // BATCH * SEQ
#define NXP   68        // DT_RANK + 2*D_STATE
#define DTR   64        // DT_RANK
#define NCH   4096      // BATCH * DI channels for scan
#define CHUNK 32
#define NCHK  128       // SEQ / CHUNK

__device__ __forceinline__ float bf2f(u16 v) {
  union { unsigned u; float f; } x; x.u = ((unsigned)v) << 16; return x.f;
}
__device__ __forceinline__ u16 f2bf(float f) {
  unsigned u = __float_as_uint(f);
  return (u16)((u + 0x7FFFu + ((u >> 16) & 1u)) >> 16);   // RNE
}

// async global->LDS DMA, 16B/lane; LDS dest = wave-uniform base + lane*16
__device__ __forceinline__ void g2l16(const u16* g, u16* l) {
  __builtin_amdgcn_global_load_lds(
      (const __attribute__((address_space(1))) unsigned int*)g,
      (__attribute__((address_space(3))) unsigned int*)l, 16, 0, 0);
}

// raw wait+barrier: vmcnt(N) keeps newer LDS-DMA deposits in flight across
// the barrier (AITER-style). 0x0074 = vmcnt(4) expcnt(7) lgkmcnt(0);
// 0x0070 = vmcnt(0) expcnt(7) lgkmcnt(0).
#define WAITBAR(imm) do {                           \
    __asm__ __volatile__("" ::: "memory");          \
    __builtin_amdgcn_s_waitcnt(imm);                \
    __builtin_amdgcn_s_barrier();                   \
    __asm__ __volatile__("" ::: "memory");          \
  } while (0)

// ---------------------------------------------------------------------------
// Input dtype detection (f32 inputs -> low u16 has huge bf16 exponents)
// ---------------------------------------------------------------------------
__global__ __launch_bounds__(256)
void detect_kernel(const u16* __restrict__ x, int* __restrict__ flag)
{
  __shared__ int tot;
  if (threadIdx.x == 0) tot = 0;
  __syncthreads();
  int cnt = 0;
  for (int i = threadIdx.x; i < 4096; i += 256) {
    const int e = (x[2 * i] >> 7) & 0xFF;
    if (e > 167) cnt++;
  }
  atomicAdd(&tot, cnt);
  __syncthreads();
  if (threadIdx.x == 0) flag[0] = (tot >= 8) ? 1 : 0;
}

// ---------------------------------------------------------------------------
// ONE conversion launch. Blocks < NBB: 6 big weights, 8 elems/thread (no-op
// when inputs are bf16). Blocks >= NBB: 11 small vectors incl. conv_w
// transpose to [4][DI] (always runs).
// ---------------------------------------------------------------------------
#define NW0 4194304   // w_in
#define NW1  139264   // w_xproj
#define NW2  131072   // w_dt
#define NW3 2097152   // w_out
#define NW4 1048576   // ffn_w1
#define NW5 1048576   // ffn_w2
#define NBB 4228      // ceil((sum NW)/8/256)
__global__ __launch_bounds__(256)
void convert_all(const float* __restrict__ s0, const float* __restrict__ s1,
                 const float* __restrict__ s2, const float* __restrict__ s3,
                 const float* __restrict__ s4, const float* __restrict__ s5,
                 u16* __restrict__ d0, u16* __restrict__ d1, u16* __restrict__ d2,
                 u16* __restrict__ d3, u16* __restrict__ d4, u16* __restrict__ d5,
                 const void* t0, const void* t1, const void* t2, const void* t3,
                 const void* t4, const void* t5, const void* t6, const void* t7,
                 const void* t8, const void* t9, const void* t10,
                 u16* __restrict__ dsm, const int* __restrict__ flag)
{
  if (blockIdx.x >= NBB) {
    const int i = (blockIdx.x - NBB) * 256 + threadIdx.x;
    if (i >= 24576) return;
    const void* src; int off; int dsti = i;
    if      (i < 8192)  { src = t0;  off = i;
                          dsti = (off & 3) * DI + (off >> 2); }  // conv_w -> [j][d]
    else if (i < 10240) { src = t1;  off = i - 8192; }   // conv_b
    else if (i < 12288) { src = t2;  off = i - 10240; }  // b_dt
    else if (i < 16384) { src = t3;  off = i - 12288; }  // a_log
    else if (i < 18432) { src = t4;  off = i - 16384; }  // d_skip
    else if (i < 19456) { src = t5;  off = i - 18432; }  // ln1_g
    else if (i < 20480) { src = t6;  off = i - 19456; }  // ln1_b
    else if (i < 21504) { src = t7;  off = i - 20480; }  // ln2_g
    else if (i < 22528) { src = t8;  off = i - 21504; }  // ln2_b
    else if (i < 23552) { src = t9;  off = i - 22528; }  // ffn_b1
    else                { src = t10; off = i - 23552; }  // ffn_b2
    dsm[dsti] = (*flag) ? f2bf(((const float*)src)[off]) : ((const u16*)src)[off];
    return;
  }
  if (*flag == 0) return;
  long e = ((long)blockIdx.x * 256 + threadIdx.x) * 8;
  const long c1 = NW0, c2 = c1 + NW1, c3 = c2 + NW2, c4 = c3 + NW3,
             c5 = c4 + NW4, c6 = c5 + NW5;
  if (e >= c6) return;
  const float* s; u16* d;
  if      (e < c1) { s = s0;          d = d0; }
  else if (e < c2) { s = s1; e -= c1; d = d1; }
  else if (e < c3) { s = s2; e -= c2; d = d2; }
  else if (e < c4) { s = s3; e -= c3; d = d3; }
  else if (e < c5) { s = s4; e -= c4; d = d4; }
  else             { s = s5; e -= c5; d = d5; }
  f32x4 a = *(const f32x4*)(s + e);
  f32x4 b = *(const f32x4*)(s + e + 4);
  u16x8 o;
#pragma unroll
  for (int k = 0; k < 4; ++k) { o[k] = f2bf(a[k]); o[4 + k] = f2bf(b[k]); }
  *(u16x8*)(d + e) = o;
}

// ---------------------------------------------------------------------------
// LayerNorm: 2 rows per block, 8 elems per thread, vectorized loads/stores.
// MODE 0: input dtype per runtime flag (LN1). MODE 1: bf16 always (LN2).
// ---------------------------------------------------------------------------
template<int MODE>
__global__ __launch_bounds__(256)
void ln_kernel(const void* __restrict__ xin, const u16* __restrict__ gw,
               const u16* __restrict__ bw, u16* __restrict__ outp,
               const int* __restrict__ flag)
{
  const int tid = threadIdx.x;
  const int sub = tid >> 7;                  // row within block
  const int col0 = (tid & 127) * 8;
  const int row = blockIdx.x * 2 + sub;
  const bool isf32 = (MODE == 0) ? (*flag != 0) : false;
  float v[8];
  if (isf32) {
    const float* xf = (const float*)xin + (size_t)row * DM + col0;
    f32x4 a = *(const f32x4*)xf, b2 = *(const f32x4*)(xf + 4);
#pragma unroll
    for (int k = 0; k < 4; ++k) { v[k] = a[k]; v[4 + k] = b2[k]; }
  } else {
    u16x8 xb = *(const u16x8*)((const u16*)xin + (size_t)row * DM + col0);
#pragma unroll
    for (int k = 0; k < 8; ++k) v[k] = bf2f(xb[k]);
  }
  float s = 0.f, s2 = 0.f;
#pragma unroll
  for (int k = 0; k < 8; ++k) { s += v[k]; s2 += v[k] * v[k]; }
#pragma unroll
  for (int off = 32; off > 0; off >>= 1) {
    s  += __shfl_down(s,  off);
    s2 += __shfl_down(s2, off);
  }
  __shared__ float red[4], red2[4];
  __shared__ f32x2 stat[2];
  const int wv = tid >> 6;
  if ((tid & 63) == 0) { red[wv] = s; red2[wv] = s2; }
  __syncthreads();
  if ((tid & 127) == 0) {
    float ts = red[sub * 2] + red[sub * 2 + 1];
    float t2 = red2[sub * 2] + red2[sub * 2 + 1];
    float mu = ts * (1.f / DM);
    float var = t2 * (1.f / DM) - mu * mu;
    stat[sub] = f32x2{mu, rsqrtf(var + 1e-5f)};
  }
  __syncthreads();
  const float mu = stat[sub][0], rs = stat[sub][1];
  u16x8 gv = *(const u16x8*)(gw + col0), bv = *(const u16x8*)(bw + col0);
  u16x8 o;
#pragma unroll
  for (int k = 0; k < 8; ++k)
    o[k] = f2bf((v[k] - mu) * rs * bf2f(gv[k]) + bf2f(bv[k]));
  *(u16x8*)(outp + (size_t)row * DM + col0) = o;
}

// ---------------------------------------------------------------------------
// bf16 MFMA GEMM: C[M,N] = A[M,K] @ B[N,K]^T.  128x128 tile, BK=32.
// 3-buffer LDS-DMA pipeline: at top of phase k, tiles k and k+1 are in flight
// (8 deposits); WAITBAR(vmcnt(4)) retires tile k's 4 while k+1 stays in
// flight across the barrier — deposits get a 2-phase head start. Tile k+2 is
// issued after the barrier into the buffer read in phase k-1 (safe: those
// ds_reads retired before the lgkm-fenced barrier). Last phase: vmcnt(0).
// Fetch-side XOR lane->chunk swizzle keeps LDS reads conflict-free (q^rsw).
// Requires: M%128==0, N%128==0, K%32==0, gridDim.x == (N/128)*64, N/128==1<<LNBX.
// EPI: 1 bf16 | 2 +bias,softplus->bf16 | 3 +x(flag dtype)->bf16 |
//      4 +bias,relu->bf16 | 5 +bias+addbf16 -> out(bf16/f32 per flag) |
//      6 split store: col<DI -> Cp (bf16), else -> Cp2 (bf16), row stride DI
// ---------------------------------------------------------------------------
template<int EPI, int LNBX>
__global__ __launch_bounds__(256, 2)
void gemm_kernel(const u16* __restrict__ A, const u16* __restrict__ Bc,
                 const u16* __restrict__ Braw,
                 int M, int N, int K,
                 const u16* __restrict__ bias, const u16* __restrict__ addbf,
                 const float* __restrict__ addf, const int* __restrict__ dtflag,
                 void* __restrict__ Cp, void* __restrict__ Cp2)
{
  __shared__ __align__(16) u16 sA[3][128 * 32];
  __shared__ __align__(16) u16 sB[3][128 * 32];
  const int fl = *dtflag;
  const u16* __restrict__ B = fl ? Bc : Braw;
  const int tid = threadIdx.x;
  const int b = blockIdx.x;
  const int xcd = b & 7;
  const int kk = b >> 3;
  const int bx = kk & ((1 << LNBX) - 1);
  const int by = xcd * 8 + (kk >> LNBX);
  const int m0 = by * 128;
  const int n0 = bx * 128;
  const int lane = tid & 63;
  const int wv = tid >> 6;
  const int wm = (wv & 1) * 64;
  const int wn = (wv >> 1) * 64;
  const int r = lane & 15;
  const int q = lane >> 4;
  const int rsw = (r >> 1) & 3;        // read-side bank swizzle

  const int pr = lane >> 2;            // 0..15 row in 16-row staging chunk
  const int kc = (lane & 3) ^ ((pr >> 1) & 3);   // swizzled source k-chunk
  const int pk = kc * 8;
  const int ls0 = (wv * 2 + 0) * 512;  // wave deposit slots within a buffer
  const int ls1 = (wv * 2 + 1) * 512;
  const u16* gA0 = A + (size_t)(m0 + wv * 32 + pr) * K + pk;
  const u16* gA1 = gA0 + (size_t)16 * K;
  const u16* gB0 = B + (size_t)(n0 + wv * 32 + pr) * K + pk;
  const u16* gB1 = gB0 + (size_t)16 * K;

#define ISSUE(bb) { g2l16(gA0, &sA[bb][ls0]); g2l16(gA1, &sA[bb][ls1]);   \
                    g2l16(gB0, &sB[bb][ls0]); g2l16(gB1, &sB[bb][ls1]);   \
                    gA0 += 32; gA1 += 32; gB0 += 32; gB1 += 32; }

  f32x4 acc[4][4];
#pragma unroll
  for (int i = 0; i < 4; ++i)
#pragma unroll
    for (int j = 0; j < 4; ++j)
#pragma unroll
      for (int t = 0; t < 4; ++t) acc[i][j][t] = 0.f;

  const int nk = K >> 5;
  ISSUE(0);                            // tile 0 -> buf 0
  if (nk > 1) ISSUE(1);                // tile 1 -> buf 1 (in flight)

  int cur = 0;
  for (int kt = 0; kt < nk; ++kt) {
    if (kt + 1 < nk) { WAITBAR(0x0074); }   // tile kt landed; kt+1 in flight
    else             { WAITBAR(0x0070); }   // last tile: full drain
    bf16x8 af[4], bfr[4];
#pragma unroll
    for (int i = 0; i < 4; ++i)
      af[i] = *reinterpret_cast<const bf16x8*>(
          &sA[cur][(wm + i * 16 + r) * 32 + (q ^ rsw) * 8]);
#pragma unroll
    for (int j = 0; j < 4; ++j)
      bfr[j] = *reinterpret_cast<const bf16x8*>(
          &sB[cur][(wn + j * 16 + r) * 32 + (q ^ rsw) * 8]);
    if (kt + 2 < nk) {
      const int nb = (cur == 0) ? 2 : cur - 1;   // == (cur+2)%3
      ISSUE(nb);
    }
#pragma unroll
    for (int i = 0; i < 4; ++i)
#pragma unroll
      for (int j = 0; j < 4; ++j)
        acc[i][j] = __builtin_amdgcn_mfma_f32_16x16x32_bf16(af[i], bfr[j], acc[i][j], 0, 0, 0);
    cur = (cur == 2) ? 0 : cur + 1;
  }
#undef ISSUE

  // epilogue: D row = wm+i*16+q*4+t (M), col = wn+j*16+r (N)
#pragma unroll
  for (int i = 0; i < 4; ++i) {
#pragma unroll
    for (int j = 0; j < 4; ++j) {
#pragma unroll
      for (int t = 0; t < 4; ++t) {
        const int row = m0 + wm + i * 16 + q * 4 + t;
        const int col = n0 + wn + j * 16 + r;
        float v = acc[i][j][t];
        if (EPI == 6) {
          const size_t rb = (size_t)row * DI;
          if (col < DI) ((u16*)Cp)[rb + col] = f2bf(v);
          else          ((u16*)Cp2)[rb + col - DI] = f2bf(v);
        } else {
          const size_t idx = (size_t)row * N + col;
          if (EPI == 1) {
            ((u16*)Cp)[idx] = f2bf(v);
          } else if (EPI == 2) {           // dt = softplus(v + b_dt)
            v += bf2f(bias[col]);
            v = (v > 15.f) ? v : __logf(1.f + __expf(v));
            ((u16*)Cp)[idx] = f2bf(v);
          } else if (EPI == 3) {           // h = x + mamba_out -> bf16
            v += fl ? addf[idx] : bf2f(addbf[idx]);
            ((u16*)Cp)[idx] = f2bf(v);
          } else if (EPI == 4) {           // relu(v + b1)
            v += bf2f(bias[col]);
            ((u16*)Cp)[idx] = f2bf(fmaxf(v, 0.f));
          } else {                         // out = h(bf16) + v + b2
            v += bf2f(bias[col]) + bf2f(addbf[idx]);
            if (fl) ((float*)Cp)[idx] = v;
            else    ((u16*)Cp)[idx] = f2bf(v);
          }
        }
      }
    }
  }
}

// ---------------------------------------------------------------------------
// x_proj split-K: part[z] = u[:, z*256:(z+1)*256] @ w_xproj[:, same]^T
// grid (8, 64). Output f32 partials [8, NTOK, 68]. Same 3-buffer pipeline.
// ---------------------------------------------------------------------------
__global__ __launch_bounds__(256, 2)
void xproj_splitk(const u16* __restrict__ A, const u16* __restrict__ Bc,
                  const u16* __restrict__ Braw, const int* __restrict__ dtflag,
                  float* __restrict__ part)
{
  __shared__ __align__(16) u16 sA[3][128 * 32];
  __shared__ __align__(16) u16 sB[3][128 * 32];
  const int fl = *dtflag;
  const u16* __restrict__ B = fl ? Bc : Braw;
  const int tid = threadIdx.x;
  const int kz = blockIdx.x;           // 0..7
  const int m0 = blockIdx.y * 128;
  const int kbase = kz * 256;
  const int lane = tid & 63;
  const int wv = tid >> 6;
  const int wm = (wv & 1) * 64;
  const int wn = (wv >> 1) * 64;
  const int r = lane & 15;
  const int q = lane >> 4;
  const int rsw = (r >> 1) & 3;
  const int pr = lane >> 2;
  const int kc = (lane & 3) ^ ((pr >> 1) & 3);
  const int pk = kc * 8;
  const int ls0 = (wv * 2 + 0) * 512;
  const int ls1 = (wv * 2 + 1) * 512;

  int br0 = wv * 32 + pr;      if (br0 > 67) br0 = 67;   // junk cols unused
  int br1 = wv * 32 + 16 + pr; if (br1 > 67) br1 = 67;
  const u16* gA0 = A + (size_t)(m0 + wv * 32 + pr) * DI + kbase + pk;
  const u16* gA1 = gA0 + (size_t)16 * DI;
  const u16* gB0 = B + (size_t)br0 * DI + kbase + pk;
  const u16* gB1 = B + (size_t)br1 * DI + kbase + pk;

#define ISSUE(bb) { g2l16(gA0, &sA[bb][ls0]); g2l16(gA1, &sA[bb][ls1]);   \
                    g2l16(gB0, &sB[bb][ls0]); g2l16(gB1, &sB[bb][ls1]);   \
                    gA0 += 32; gA1 += 32; gB0 += 32; gB1 += 32; }

  f32x4 acc[4][4];
#pragma unroll
  for (int i = 0; i < 4; ++i)
#pragma unroll
    for (int j = 0; j < 4; ++j)
#pragma unroll
      for (int t = 0; t < 4; ++t) acc[i][j][t] = 0.f;

  ISSUE(0);
  ISSUE(1);

  int cur = 0;
  for (int kt = 0; kt < 8; ++kt) {
    if (kt + 1 < 8) { WAITBAR(0x0074); }
    else            { WAITBAR(0x0070); }
    bf16x8 af[4], bfr[4];
#pragma unroll
    for (int i = 0; i < 4; ++i)
      af[i] = *reinterpret_cast<const bf16x8*>(
          &sA[cur][(wm + i * 16 + r) * 32 + (q ^ rsw) * 8]);
#pragma unroll
    for (int j = 0; j < 4; ++j)
      bfr[j] = *reinterpret_cast<const bf16x8*>(
          &sB[cur][(wn + j * 16 + r) * 32 + (q ^ rsw) * 8]);
    if (kt + 2 < 8) {
      const int nb = (cur == 0) ? 2 : cur - 1;
      ISSUE(nb);
    }
#pragma unroll
    for (int i = 0; i < 4; ++i)
#pragma unroll
      for (int j = 0; j < 4; ++j)
        acc[i][j] = __builtin_amdgcn_mfma_f32_16x16x32_bf16(af[i], bfr[j], acc[i][j], 0, 0, 0);
    cur = (cur == 2) ? 0 : cur + 1;
  }
#undef ISSUE

#pragma unroll
  for (int i = 0; i < 4; ++i)
#pragma unroll
    for (int j = 0; j < 4; ++j)
#pragma unroll
      for (int t = 0; t < 4; ++t) {
        const int row = m0 + wm + i * 16 + q * 4 + t;
        const int col = wn + j * 16 + r;
        if (col < NXP)
          part[((size_t)kz * NTOK + row) * NXP + col] = acc[i][j][t];
      }
}

// Reduce partials: cols 0..63 -> dtraw bf16 [NTOK,64]; 64..67 -> bc f32 [NTOK,4]
__global__ __launch_bounds__(256)
void xreduce_kernel(const float* __restrict__ part, u16* __restrict__ dtraw,
                    float* __restrict__ bc)
{
  const int i = blockIdx.x * 256 + threadIdx.x;
  if (i >= NTOK * NXP) return;
  const int row = i / NXP, col = i - row * NXP;
  float s = 0.f;
#pragma unroll
  for (int z = 0; z < 8; ++z) s += part[(size_t)z * NTOK * NXP + i];
  if (col < DTR) dtraw[(size_t)row * DTR + col] = f2bf(s);
  else           bc[row * 4 + (col - DTR)] = s;
}

// ---------------------------------------------------------------------------
// Depthwise causal conv (k=4, transposed weights) + bias + SiLU, x8 vectorized.
// ---------------------------------------------------------------------------
__global__ __launch_bounds__(256)
void conv_silu_kernel(const u16* __restrict__ xp, const u16* __restrict__ cwT,
                      const u16* __restrict__ cb, u16* __restrict__ u)
{
  const int token = blockIdx.x;
  const int t = token & (SEQ - 1);
  const int d0 = threadIdx.x * 8;
  const ptrdiff_t base = (ptrdiff_t)token * DI + d0;
  float acc[8];
  u16x8 cbv = *(const u16x8*)(cb + d0);
#pragma unroll
  for (int k = 0; k < 8; ++k) acc[k] = bf2f(cbv[k]);
#pragma unroll
  for (int j = 0; j < 4; ++j) {
    if (t - 3 + j >= 0) {
      u16x8 xv = *(const u16x8*)(xp + base + (ptrdiff_t)(j - 3) * DI);
      u16x8 wv = *(const u16x8*)(cwT + j * DI + d0);
#pragma unroll
      for (int k = 0; k < 8; ++k) acc[k] += bf2f(wv[k]) * bf2f(xv[k]);
    }
  }
  u16x8 o;
#pragma unroll
  for (int k = 0; k < 8; ++k) {
    const float sg = 1.f / (1.f + __expf(-acc[k]));
    o[k] = f2bf(acc[k] * sg);
  }
  *(u16x8*)(u + base) = o;
}

// ---------------------------------------------------------------------------
// Chunked SSM scan (N=2 states), 4 channels per thread, CHUNK=32.
// ---------------------------------------------------------------------------
__global__ __launch_bounds__(256)
void scan_pass1(const u16* __restrict__ dtb, const u16* __restrict__ ub,
                const float* __restrict__ bc, const u16* __restrict__ a_log,
                float* __restrict__ S, float* __restrict__ hf0, float* __restrict__ hf1)
{
  const int g4 = blockIdx.x * 256 + threadIdx.x;   // NCHK*NCH/4
  const int chg = g4 & (NCH / 4 - 1);
  const int c = g4 >> 10;
  const int ch0 = chg * 4;
  const int b = ch0 >> 11;
  const int d0 = ch0 & (DI - 1);
  u16x8 av = *(const u16x8*)(a_log + d0 * 2);
  float A0[4], A1[4];
#pragma unroll
  for (int k = 0; k < 4; ++k) {
    A0[k] = -__expf(bf2f(av[2 * k]));
    A1[k] = -__expf(bf2f(av[2 * k + 1]));
  }
  float h0[4] = {0.f, 0.f, 0.f, 0.f}, h1[4] = {0.f, 0.f, 0.f, 0.f};
  float s[4] = {0.f, 0.f, 0.f, 0.f};
  const int row0 = b * SEQ + c * CHUNK;
  for (int i = 0; i < CHUNK; ++i) {
    const size_t row = row0 + i;
    u16x4 dtv = *(const u16x4*)(dtb + row * DI + d0);
    u16x4 uv  = *(const u16x4*)(ub + row * DI + d0);
    f32x2 Bv = *(const f32x2*)(bc + row * 4);
#pragma unroll
    for (int k = 0; k < 4; ++k) {
      const float dt = bf2f(dtv[k]);
      const float dtu = dt * bf2f(uv[k]);
      h0[k] = __expf(A0[k] * dt) * h0[k] + dtu * Bv[0];
      h1[k] = __expf(A1[k] * dt) * h1[k] + dtu * Bv[1];
      s[k] += dt;
    }
  }
  const size_t g0 = (size_t)c * NCH + ch0;
  *(f32x4*)(S + g0)   = f32x4{s[0], s[1], s[2], s[3]};
  *(f32x4*)(hf0 + g0) = f32x4{h0[0], h0[1], h0[2], h0[3]};
  *(f32x4*)(hf1 + g0) = f32x4{h1[0], h1[1], h1[2], h1[3]};
}

__global__ __launch_bounds__(256)
void scan_pass2(const float* __restrict__ S, const float* __restrict__ hf0,
                const float* __restrict__ hf1, const u16* __restrict__ a_log,
                float* __restrict__ hi0, float* __restrict__ hi1)
{
  const int ch = blockIdx.x * 256 + threadIdx.x;  // NCH
  const int d = ch & (DI - 1);
  const float A0 = -__expf(bf2f(a_log[d * 2 + 0]));
  const float A1 = -__expf(bf2f(a_log[d * 2 + 1]));
  float h0 = 0.f, h1 = 0.f;
  // software-pipelined: prefetch next chunk's state while combining current
  size_t g = ch;
  float sv = S[g], f0 = hf0[g], f1 = hf1[g];
  for (int c = 0; c < NCHK; ++c) {
    float svn = 0.f, f0n = 0.f, f1n = 0.f;
    if (c + 1 < NCHK) {
      const size_t gn = g + NCH;
      svn = S[gn]; f0n = hf0[gn]; f1n = hf1[gn];
    }
    hi0[g] = h0; hi1[g] = h1;
    h0 = __expf(A0 * sv) * h0 + f0;
    h1 = __expf(A1 * sv) * h1 + f1;
    sv = svn; f0 = f0n; f1 = f1n;
    g += NCH;
  }
}

__global__ __launch_bounds__(256)
void scan_pass3(const u16* __restrict__ dtb, const u16* __restrict__ ub,
                const float* __restrict__ bc, const u16* __restrict__ zbuf,
                const u16* __restrict__ a_log, const u16* __restrict__ d_skip,
                const float* __restrict__ hi0, const float* __restrict__ hi1,
                u16* __restrict__ yb)
{
  const int g4 = blockIdx.x * 256 + threadIdx.x;
  const int chg = g4 & (NCH / 4 - 1);
  const int c = g4 >> 10;
  const int ch0 = chg * 4;
  const int b = ch0 >> 11;
  const int d0 = ch0 & (DI - 1);
  u16x8 av = *(const u16x8*)(a_log + d0 * 2);
  u16x4 dkv = *(const u16x4*)(d_skip + d0);
  float A0[4], A1[4], dsk[4];
#pragma unroll
  for (int k = 0; k < 4; ++k) {
    A0[k] = -__expf(bf2f(av[2 * k]));
    A1[k] = -__expf(bf2f(av[2 * k + 1]));
    dsk[k] = bf2f(dkv[k]);
  }
  const size_t g0 = (size_t)c * NCH + ch0;
  f32x4 h0v = *(const f32x4*)(hi0 + g0);
  f32x4 h1v = *(const f32x4*)(hi1 + g0);
  float h0[4], h1[4];
#pragma unroll
  for (int k = 0; k < 4; ++k) { h0[k] = h0v[k]; h1[k] = h1v[k]; }
  const int row0 = b * SEQ + c * CHUNK;
  for (int i = 0; i < CHUNK; ++i) {
    const size_t row = row0 + i;
    u16x4 dtv = *(const u16x4*)(dtb + row * DI + d0);
    u16x4 uv  = *(const u16x4*)(ub + row * DI + d0);
    u16x4 zv  = *(const u16x4*)(zbuf + row * DI + d0);
    f32x4 bcv = *(const f32x4*)(bc + row * 4);
    u16x4 o;
#pragma unroll
    for (int k = 0; k < 4; ++k) {
      const float dt = bf2f(dtv[k]);
      const float uu = bf2f(uv[k]);
      const float dtu = dt * uu;
      h0[k] = __expf(A0[k] * dt) * h0[k] + dtu * bcv[0];
      h1[k] = __expf(A1[k] * dt) * h1[k] + dtu * bcv[1];
      const float y = h0[k] * bcv[2] + h1[k] * bcv[3];
      const float z = bf2f(zv[k]);
      const float sz = z / (1.f + __expf(-z));
      o[k] = f2bf((y + dsk[k] * uu) * sz);
    }
    *(u16x4*)(yb + row * DI + d0) = o;    // in-place over dtb: ok
  }
}

// ---------------------------------------------------------------------------
extern "C" void kernel_launch(void* const* d_in, const int* in_sizes, int n_in,
                              void* d_out, int out_size, void* d_ws, size_t ws_size,
                              hipStream_t stream)
{
  const void* x       = d_in[0];
  const void* w_in    = d_in[1];
  const void* conv_w  = d_in[2];
  const void* conv_b  = d_in[3];
  const void* w_xproj = d_in[4];
  const void* w_dt    = d_in[5];
  const void* b_dt    = d_in[6];
  const void* a_log   = d_in[7];
  const void* d_skip  = d_in[8];
  const void* w_out   = d_in[9];
  const void* ln1_g   = d_in[10];
  const void* ln1_b   = d_in[11];
  const void* ln2_g   = d_in[12];
  const void* ln2_b   = d_in[13];
  const void* ffn_w1  = d_in[14];
  const void* ffn_b1  = d_in[15];
  const void* ffn_w2  = d_in[16];
  const void* ffn_b2  = d_in[17];
  char* ws = (char*)d_ws;

  // ---- workspace layout (high-water ~127 MB) ----
  const size_t o_flag  = 0;
  const size_t o_small = 256;
  const size_t o_cwout = o_small + 65536;
  const size_t o_cff1  = o_cwout + (size_t)DM * DI * 2;
  const size_t o_cff2  = o_cff1  + (size_t)DM * DM * 2;
  const size_t o_cxp   = o_cff2  + (size_t)DM * DM * 2;
  const size_t o_cwdt  = o_cxp   + (size_t)NXP * DI * 2;
  const size_t o_xn    = 9437184;                         // 16 MiB region
  const size_t o_xp    = o_xn + (size_t)NTOK * DM * 2;    // 32 MiB
  const size_t o_z     = o_xp + (size_t)NTOK * DI * 2;    // 32 MiB
  const size_t o_u     = o_z  + (size_t)NTOK * DI * 2;    // 32 MiB
  const size_t o_bc    = o_u  + (size_t)NTOK * DI * 2;    // 128 KiB
  // scan state overlays the xn region (dead during the scan):
  const size_t SCN = (size_t)NCHK * NCH * 4;              // 2 MiB each
  const size_t o_S   = o_xn + 0 * SCN;
  const size_t o_hf0 = o_xn + 1 * SCN;
  const size_t o_hf1 = o_xn + 2 * SCN;
  const size_t o_hi0 = o_xn + 3 * SCN;
  const size_t o_hi1 = o_xn + 4 * SCN;                    // ends +10 MiB < 16 MiB

  int*   flagp   = (int*)(ws + o_flag);
  u16*   csmall  = (u16*)(ws + o_small);
  u16*   c_cwT   = csmall +     0;       // transposed conv weights [4][DI]
  u16*   c_convb = csmall +  8192;
  u16*   c_bdt   = csmall + 10240;
  u16*   c_alog  = csmall + 12288;
  u16*   c_dskip = csmall + 16384;
  u16*   c_ln1g  = csmall + 18432;
  u16*   c_ln1b  = csmall + 19456;
  u16*   c_ln2g  = csmall + 20480;
  u16*   c_ln2b  = csmall + 21504;
  u16*   c_fb1   = csmall + 22528;
  u16*   c_fb2   = csmall + 23552;
  u16*   c_wout  = (u16*)(ws + o_cwout);
  u16*   c_ff1   = (u16*)(ws + o_cff1);
  u16*   c_ff2   = (u16*)(ws + o_cff2);
  u16*   c_xproj = (u16*)(ws + o_cxp);
  u16*   c_wdt   = (u16*)(ws + o_cwdt);
  u16*   c_win   = (u16*)(ws + o_u);     // overlays u (dead until conv)
  u16*   xn      = (u16*)(ws + o_xn);
  u16*   xp      = (u16*)(ws + o_xp);
  u16*   zb      = (u16*)(ws + o_z);
  u16*   u       = (u16*)(ws + o_u);
  float* part    = (float*)(ws + o_xp);  // overlays xp (dead after conv)
  u16*   dtraw   = (u16*)(ws + o_xn);    // overlays xn (dead after in_proj)
  u16*   dtb     = xp;                   // overlays part (dead after reduce)
  u16*   yb      = xp;
  float* bc      = (float*)(ws + o_bc);
  float* S       = (float*)(ws + o_S);   // scan arrays overlay xn region
  float* hf0     = (float*)(ws + o_hf0);
  float* hf1     = (float*)(ws + o_hf1);
  float* hi0     = (float*)(ws + o_hi0);
  float* hi1     = (float*)(ws + o_hi1);
  u16*   hb      = (u16*)(ws + o_z);     // h as bf16, overlays z (dead after pass3)
  u16*   hn      = (u16*)(ws + o_xn);    // overlays scan arrays (dead)
  u16*   f1      = (u16*)(ws + o_u);     // overlays u (dead)

  const dim3 blk(256);

  // 0) detect dtype; all param conversion in ONE launch (no-op weights on bf16)
  detect_kernel<<<1, blk, 0, stream>>>((const u16*)x, flagp);
  convert_all<<<NBB + 96, blk, 0, stream>>>(
      (const float*)w_in, (const float*)w_xproj, (const float*)w_dt,
      (const float*)w_out, (const float*)ffn_w1, (const float*)ffn_w2,
      c_win, c_xproj, c_wdt, c_wout, c_ff1, c_ff2,
      conv_w, conv_b, b_dt, a_log, d_skip,
      ln1_g, ln1_b, ln2_g, ln2_b, ffn_b1, ffn_b2,
      csmall, flagp);

  // 1) LN1(x) -> xn
  ln_kernel<0><<<NTOK / 2, blk, 0, stream>>>(x, c_ln1g, c_ln1b, xn, flagp);
  // 2) fused in_proj: [xp | z] = xn @ w_in^T   (N=4096 -> LNBX=5, 2048 blocks)
  gemm_kernel<6, 5><<<2048, blk, 0, stream>>>(xn, c_win, (const u16*)w_in,
                                              NTOK, 2 * DI, DM,
                                              nullptr, nullptr, nullptr, flagp, xp, zb);
  // 3) u = silu(conv(xp) + conv_b)
  conv_silu_kernel<<<NTOK, blk, 0, stream>>>(xp, c_cwT, c_convb, u);
  // 4) x_proj split-K (partials) + reduce -> dtraw (bf16), bc (f32)
  xproj_splitk<<<dim3(8, 64), blk, 0, stream>>>(u, c_xproj, (const u16*)w_xproj,
                                                flagp, part);
  xreduce_kernel<<<(NTOK * NXP + 255) / 256, blk, 0, stream>>>(part, dtraw, bc);
  // 5) dt = softplus(dtraw @ w_dt^T + b_dt)   (N=2048 -> LNBX=4, K=64 -> nk=2)
  gemm_kernel<2, 4><<<1024, blk, 0, stream>>>(dtraw, c_wdt, (const u16*)w_dt,
                                              NTOK, DI, DTR,
                                              c_bdt, nullptr, nullptr, flagp, dtb, nullptr);
  // 6) chunked scan -> yb = (y + d_skip*u) * silu(z)
  scan_pass1<<<NCHK * NCH / 4 / 256, blk, 0, stream>>>(dtb, u, bc, c_alog, S, hf0, hf1);
  scan_pass2<<<NCH / 256, blk, 0, stream>>>(S, hf0, hf1, c_alog, hi0, hi1);
  scan_pass3<<<NCHK * NCH / 4 / 256, blk, 0, stream>>>(dtb, u, bc, zb, c_alog, c_dskip,
                                                       hi0, hi1, yb);
  // 7) h = bf16(x + yb @ w_out^T)   (N=1024 -> LNBX=3)
  gemm_kernel<3, 3><<<512, blk, 0, stream>>>(yb, c_wout, (const u16*)w_out,
                                             NTOK, DM, DI,
                                             nullptr, (const u16*)x, (const float*)x,
                                             flagp, hb, nullptr);
  // 8) LN2(h) -> hn   (bf16 input)
  ln_kernel<1><<<NTOK / 2, blk, 0, stream>>>(hb, c_ln2g, c_ln2b, hn, flagp);
  // 9) f1 = relu(hn @ ffn_w1^T + b1)
  gemm_kernel<4, 3><<<512, blk, 0, stream>>>(hn, c_ff1, (const u16*)ffn_w1,
                                             NTOK, DM, DM,
                                             c_fb1, nullptr, nullptr, flagp, f1, nullptr);
  // 10) out = h + f1 @ ffn_w2^T + b2   (h read as bf16)
  gemm_kernel<5, 3><<<512, blk, 0, stream>>>(f1, c_ff2, (const u16*)ffn_w2,
                                             NTOK, DM, DM,
                                             c_fb2, hb, nullptr, flagp, d_out, nullptr);
}

// Round 10
// 466.110 us; speedup vs baseline: 2.0726x; 1.0367x over previous
//
#include <hip/hip_runtime.h>

typedef unsigned short u16;
typedef __bf16 bf16x8 __attribute__((ext_vector_type(8)));
typedef float f32x4 __attribute__((ext_vector_type(4)));
typedef float f32x2 __attribute__((ext_vector_type(2)));
typedef u16 u16x4 __attribute__((ext_vector_type(4)));
typedef u16 u16x8 __attribute__((ext_vector_type(8)));

// Problem constants
#define SEQ   4096
#define DM    1024
#define DI    2048
#define NTOK  8192      // BATCH * SEQ
#define NXP   68        // DT_RANK + 2*D_STATE
#define DTR   64        // DT_RANK
#define NCH   4096      // BATCH * DI channels for scan
#define CHUNK 32
#define NCHK  128       // SEQ / CHUNK

__device__ __forceinline__ float bf2f(u16 v) {
  union { unsigned u; float f; } x; x.u = ((unsigned)v) << 16; return x.f;
}
__device__ __forceinline__ u16 f2bf(float f) {
  unsigned u = __float_as_uint(f);
  return (u16)((u + 0x7FFFu + ((u >> 16) & 1u)) >> 16);   // RNE
}

// async global->LDS DMA, 16B/lane; LDS dest = wave-uniform base + lane*16
__device__ __forceinline__ void g2l16(const u16* g, u16* l) {
  __builtin_amdgcn_global_load_lds(
      (const __attribute__((address_space(1))) unsigned int*)g,
      (__attribute__((address_space(3))) unsigned int*)l, 16, 0, 0);
}

// ---------------------------------------------------------------------------
// Input dtype detection (f32 inputs -> low u16 has huge bf16 exponents)
// ---------------------------------------------------------------------------
__global__ __launch_bounds__(256)
void detect_kernel(const u16* __restrict__ x, int* __restrict__ flag)
{
  __shared__ int tot;
  if (threadIdx.x == 0) tot = 0;
  __syncthreads();
  int cnt = 0;
  for (int i = threadIdx.x; i < 4096; i += 256) {
    const int e = (x[2 * i] >> 7) & 0xFF;
    if (e > 167) cnt++;
  }
  atomicAdd(&tot, cnt);
  __syncthreads();
  if (threadIdx.x == 0) flag[0] = (tot >= 8) ? 1 : 0;
}

// ---------------------------------------------------------------------------
// ONE conversion launch. Blocks < NBB: 6 big weights, 8 elems/thread (no-op
// when inputs are bf16). Blocks >= NBB: 11 small vectors incl. conv_w
// transpose to [4][DI] (always runs).
// ---------------------------------------------------------------------------
#define NW0 4194304   // w_in
#define NW1  139264   // w_xproj
#define NW2  131072   // w_dt
#define NW3 2097152   // w_out
#define NW4 1048576   // ffn_w1
#define NW5 1048576   // ffn_w2
#define NBB 4228      // ceil((sum NW)/8/256)
__global__ __launch_bounds__(256)
void convert_all(const float* __restrict__ s0, const float* __restrict__ s1,
                 const float* __restrict__ s2, const float* __restrict__ s3,
                 const float* __restrict__ s4, const float* __restrict__ s5,
                 u16* __restrict__ d0, u16* __restrict__ d1, u16* __restrict__ d2,
                 u16* __restrict__ d3, u16* __restrict__ d4, u16* __restrict__ d5,
                 const void* t0, const void* t1, const void* t2, const void* t3,
                 const void* t4, const void* t5, const void* t6, const void* t7,
                 const void* t8, const void* t9, const void* t10,
                 u16* __restrict__ dsm, const int* __restrict__ flag)
{
  if (blockIdx.x >= NBB) {
    const int i = (blockIdx.x - NBB) * 256 + threadIdx.x;
    if (i >= 24576) return;
    const void* src; int off; int dsti = i;
    if      (i < 8192)  { src = t0;  off = i;
                          dsti = (off & 3) * DI + (off >> 2); }  // conv_w -> [j][d]
    else if (i < 10240) { src = t1;  off = i - 8192; }   // conv_b
    else if (i < 12288) { src = t2;  off = i - 10240; }  // b_dt
    else if (i < 16384) { src = t3;  off = i - 12288; }  // a_log
    else if (i < 18432) { src = t4;  off = i - 16384; }  // d_skip
    else if (i < 19456) { src = t5;  off = i - 18432; }  // ln1_g
    else if (i < 20480) { src = t6;  off = i - 19456; }  // ln1_b
    else if (i < 21504) { src = t7;  off = i - 20480; }  // ln2_g
    else if (i < 22528) { src = t8;  off = i - 21504; }  // ln2_b
    else if (i < 23552) { src = t9;  off = i - 22528; }  // ffn_b1
    else                { src = t10; off = i - 23552; }  // ffn_b2
    dsm[dsti] = (*flag) ? f2bf(((const float*)src)[off]) : ((const u16*)src)[off];
    return;
  }
  if (*flag == 0) return;
  long e = ((long)blockIdx.x * 256 + threadIdx.x) * 8;
  const long c1 = NW0, c2 = c1 + NW1, c3 = c2 + NW2, c4 = c3 + NW3,
             c5 = c4 + NW4, c6 = c5 + NW5;
  if (e >= c6) return;
  const float* s; u16* d;
  if      (e < c1) { s = s0;          d = d0; }
  else if (e < c2) { s = s1; e -= c1; d = d1; }
  else if (e < c3) { s = s2; e -= c2; d = d2; }
  else if (e < c4) { s = s3; e -= c3; d = d3; }
  else if (e < c5) { s = s4; e -= c4; d = d4; }
  else             { s = s5; e -= c5; d = d5; }
  f32x4 a = *(const f32x4*)(s + e);
  f32x4 b = *(const f32x4*)(s + e + 4);
  u16x8 o;
#pragma unroll
  for (int k = 0; k < 4; ++k) { o[k] = f2bf(a[k]); o[4 + k] = f2bf(b[k]); }
  *(u16x8*)(d + e) = o;
}

// ---------------------------------------------------------------------------
// LayerNorm: 2 rows per block, 8 elems per thread, vectorized loads/stores.
// MODE 0: input dtype per runtime flag (LN1). MODE 1: bf16 always (LN2).
// ---------------------------------------------------------------------------
template<int MODE>
__global__ __launch_bounds__(256)
void ln_kernel(const void* __restrict__ xin, const u16* __restrict__ gw,
               const u16* __restrict__ bw, u16* __restrict__ outp,
               const int* __restrict__ flag)
{
  const int tid = threadIdx.x;
  const int sub = tid >> 7;                  // row within block
  const int col0 = (tid & 127) * 8;
  const int row = blockIdx.x * 2 + sub;
  const bool isf32 = (MODE == 0) ? (*flag != 0) : false;
  float v[8];
  if (isf32) {
    const float* xf = (const float*)xin + (size_t)row * DM + col0;
    f32x4 a = *(const f32x4*)xf, b2 = *(const f32x4*)(xf + 4);
#pragma unroll
    for (int k = 0; k < 4; ++k) { v[k] = a[k]; v[4 + k] = b2[k]; }
  } else {
    u16x8 xb = *(const u16x8*)((const u16*)xin + (size_t)row * DM + col0);
#pragma unroll
    for (int k = 0; k < 8; ++k) v[k] = bf2f(xb[k]);
  }
  float s = 0.f, s2 = 0.f;
#pragma unroll
  for (int k = 0; k < 8; ++k) { s += v[k]; s2 += v[k] * v[k]; }
#pragma unroll
  for (int off = 32; off > 0; off >>= 1) {
    s  += __shfl_down(s,  off);
    s2 += __shfl_down(s2, off);
  }
  __shared__ float red[4], red2[4];
  __shared__ f32x2 stat[2];
  const int wv = tid >> 6;
  if ((tid & 63) == 0) { red[wv] = s; red2[wv] = s2; }
  __syncthreads();
  if ((tid & 127) == 0) {
    float ts = red[sub * 2] + red[sub * 2 + 1];
    float t2 = red2[sub * 2] + red2[sub * 2 + 1];
    float mu = ts * (1.f / DM);
    float var = t2 * (1.f / DM) - mu * mu;
    stat[sub] = f32x2{mu, rsqrtf(var + 1e-5f)};
  }
  __syncthreads();
  const float mu = stat[sub][0], rs = stat[sub][1];
  u16x8 gv = *(const u16x8*)(gw + col0), bv = *(const u16x8*)(bw + col0);
  u16x8 o;
#pragma unroll
  for (int k = 0; k < 8; ++k)
    o[k] = f2bf((v[k] - mu) * rs * bf2f(gv[k]) + bf2f(bv[k]));
  *(u16x8*)(outp + (size_t)row * DM + col0) = o;
}

// ---------------------------------------------------------------------------
// bf16 MFMA GEMM: C[M,N] = A[M,K] @ B[N,K]^T.  128x128 tile, BK=32,
// round-8 2-buffer LDS-DMA pipeline (one __syncthreads per iter), XCD
// swizzle, fetch-side XOR lane->chunk swizzle (conflict-free LDS reads).
// NEW: LDS-transpose epilogue — acc round-trips through per-wave LDS
// (stride 68 f32), read back row-major, stored as two coalesced u16x8 per
// 16-row chunk (VMEM stores 64 -> 8 per thread; vectorized bias/add loads).
// Requires: M%128==0, N%128==0, K%32==0, gridDim.x == (N/128)*64, N/128==1<<LNBX.
// EPI: 1 bf16 | 2 +bias,softplus->bf16 | 3 +x(flag dtype)->bf16 |
//      4 +bias,relu->bf16 | 5 +bias+addbf16 -> out(bf16/f32 per flag) |
//      6 split store: n0<DI -> Cp else Cp2 (block-uniform), row stride DI
// ---------------------------------------------------------------------------
template<int EPI, int LNBX>
__global__ __launch_bounds__(256, 2)
void gemm_kernel(const u16* __restrict__ A, const u16* __restrict__ Bc,
                 const u16* __restrict__ Braw,
                 int M, int N, int K,
                 const u16* __restrict__ bias, const u16* __restrict__ addbf,
                 const float* __restrict__ addf, const int* __restrict__ dtflag,
                 void* __restrict__ Cp, void* __restrict__ Cp2)
{
  __shared__ __align__(16) u16 sA[2][128 * 32];
  __shared__ __align__(16) u16 sB[2][128 * 32];
  const int fl = *dtflag;
  const u16* __restrict__ B = fl ? Bc : Braw;
  const int tid = threadIdx.x;
  const int b = blockIdx.x;
  const int xcd = b & 7;
  const int kk = b >> 3;
  const int bx = kk & ((1 << LNBX) - 1);
  const int by = xcd * 8 + (kk >> LNBX);
  const int m0 = by * 128;
  const int n0 = bx * 128;
  const int lane = tid & 63;
  const int wv = tid >> 6;
  const int wm = (wv & 1) * 64;
  const int wn = (wv >> 1) * 64;
  const int r = lane & 15;
  const int q = lane >> 4;
  const int rsw = (r >> 1) & 3;        // read-side bank swizzle

  const int pr = lane >> 2;            // 0..15 row in 16-row staging chunk
  const int kc = (lane & 3) ^ ((pr >> 1) & 3);   // swizzled source k-chunk
  const int pk = kc * 8;
  u16* lA0[2] = { &sA[0][(wv * 2 + 0) * 512], &sA[1][(wv * 2 + 0) * 512] };
  u16* lA1[2] = { &sA[0][(wv * 2 + 1) * 512], &sA[1][(wv * 2 + 1) * 512] };
  u16* lB0[2] = { &sB[0][(wv * 2 + 0) * 512], &sB[1][(wv * 2 + 0) * 512] };
  u16* lB1[2] = { &sB[0][(wv * 2 + 1) * 512], &sB[1][(wv * 2 + 1) * 512] };
  const u16* gA0 = A + (size_t)(m0 + wv * 32 + pr) * K + pk;
  const u16* gA1 = gA0 + (size_t)16 * K;
  const u16* gB0 = B + (size_t)(n0 + wv * 32 + pr) * K + pk;
  const u16* gB1 = gB0 + (size_t)16 * K;

  f32x4 acc[4][4];
#pragma unroll
  for (int i = 0; i < 4; ++i)
#pragma unroll
    for (int j = 0; j < 4; ++j)
#pragma unroll
      for (int t = 0; t < 4; ++t) acc[i][j][t] = 0.f;

  g2l16(gA0, lA0[0]); g2l16(gA1, lA1[0]);
  g2l16(gB0, lB0[0]); g2l16(gB1, lB1[0]);

  const int nk = K >> 5;
  for (int kt = 0; kt < nk; ++kt) {
    const int cur = kt & 1;
    __syncthreads();   // drains vmcnt(0): tile-kt deposits complete
    bf16x8 af[4], bfr[4];
#pragma unroll
    for (int i = 0; i < 4; ++i)
      af[i] = *reinterpret_cast<const bf16x8*>(
          &sA[cur][(wm + i * 16 + r) * 32 + (q ^ rsw) * 8]);
#pragma unroll
    for (int j = 0; j < 4; ++j)
      bfr[j] = *reinterpret_cast<const bf16x8*>(
          &sB[cur][(wn + j * 16 + r) * 32 + (q ^ rsw) * 8]);
    if (kt + 1 < nk) {
      gA0 += 32; gA1 += 32; gB0 += 32; gB1 += 32;
      g2l16(gA0, lA0[cur ^ 1]); g2l16(gA1, lA1[cur ^ 1]);
      g2l16(gB0, lB0[cur ^ 1]); g2l16(gB1, lB1[cur ^ 1]);
    }
#pragma unroll
    for (int i = 0; i < 4; ++i)
#pragma unroll
      for (int j = 0; j < 4; ++j)
        acc[i][j] = __builtin_amdgcn_mfma_f32_16x16x32_bf16(af[i], bfr[j], acc[i][j], 0, 0, 0);
  }

  // ---- LDS-transpose epilogue ----
  __syncthreads();     // all waves done with final ds_reads of sA/sB
  float* ep = (wv < 2) ? ((float*)&sA[0][0] + wv * 2048)
                       : ((float*)&sB[0][0] + (wv - 2) * 2048);
  const int r2 = lane >> 2;                      // readback row 0..15
  const int ccol = ((lane & 3) ^ (r2 & 3)) * 16; // readback col-quarter (swizzled)
  u16* C6 = nullptr; int c6off = 0;
  if (EPI == 6) { C6 = (n0 < DI) ? (u16*)Cp : (u16*)Cp2; c6off = (n0 < DI) ? 0 : DI; }

#pragma unroll
  for (int i = 0; i < 4; ++i) {
#pragma unroll
    for (int j = 0; j < 4; ++j)
#pragma unroll
      for (int t = 0; t < 4; ++t)
        ep[(q * 4 + t) * 68 + j * 16 + r] = acc[i][j][t];
    // per-wave region: compiler orders ds write->read via lgkmcnt
    f32x4 w0 = *(const f32x4*)&ep[r2 * 68 + ccol + 0];
    f32x4 w1 = *(const f32x4*)&ep[r2 * 68 + ccol + 4];
    f32x4 w2 = *(const f32x4*)&ep[r2 * 68 + ccol + 8];
    f32x4 w3 = *(const f32x4*)&ep[r2 * 68 + ccol + 12];
    float vv[16];
#pragma unroll
    for (int k = 0; k < 4; ++k) {
      vv[k] = w0[k]; vv[4 + k] = w1[k]; vv[8 + k] = w2[k]; vv[12 + k] = w3[k];
    }
    const int row = m0 + wm + i * 16 + r2;
    const int colg = n0 + wn + ccol;
    if (EPI == 6) {
      u16x8 o0, o1;
#pragma unroll
      for (int k = 0; k < 8; ++k) { o0[k] = f2bf(vv[k]); o1[k] = f2bf(vv[8 + k]); }
      const size_t cb6 = (size_t)row * DI + (colg - c6off);
      *(u16x8*)&C6[cb6] = o0;
      *(u16x8*)&C6[cb6 + 8] = o1;
    } else {
      const size_t idx = (size_t)row * N + colg;
      if (EPI == 1) {
        u16x8 o0, o1;
#pragma unroll
        for (int k = 0; k < 8; ++k) { o0[k] = f2bf(vv[k]); o1[k] = f2bf(vv[8 + k]); }
        *(u16x8*)&((u16*)Cp)[idx] = o0;
        *(u16x8*)&((u16*)Cp)[idx + 8] = o1;
      } else if (EPI == 2) {               // dt = softplus(v + b_dt)
        u16x8 b0 = *(const u16x8*)&bias[colg];
        u16x8 b1 = *(const u16x8*)&bias[colg + 8];
        u16x8 o0, o1;
#pragma unroll
        for (int k = 0; k < 8; ++k) {
          float v0 = vv[k] + bf2f(b0[k]);
          float v1 = vv[8 + k] + bf2f(b1[k]);
          v0 = (v0 > 15.f) ? v0 : __logf(1.f + __expf(v0));
          v1 = (v1 > 15.f) ? v1 : __logf(1.f + __expf(v1));
          o0[k] = f2bf(v0); o1[k] = f2bf(v1);
        }
        *(u16x8*)&((u16*)Cp)[idx] = o0;
        *(u16x8*)&((u16*)Cp)[idx + 8] = o1;
      } else if (EPI == 3) {               // h = x + v -> bf16
        float ax[16];
        if (fl) {
          f32x4 a0 = *(const f32x4*)&addf[idx];
          f32x4 a1 = *(const f32x4*)&addf[idx + 4];
          f32x4 a2 = *(const f32x4*)&addf[idx + 8];
          f32x4 a3 = *(const f32x4*)&addf[idx + 12];
#pragma unroll
          for (int k = 0; k < 4; ++k) {
            ax[k] = a0[k]; ax[4 + k] = a1[k]; ax[8 + k] = a2[k]; ax[12 + k] = a3[k];
          }
        } else {
          u16x8 a0 = *(const u16x8*)&addbf[idx];
          u16x8 a1 = *(const u16x8*)&addbf[idx + 8];
#pragma unroll
          for (int k = 0; k < 8; ++k) { ax[k] = bf2f(a0[k]); ax[8 + k] = bf2f(a1[k]); }
        }
        u16x8 o0, o1;
#pragma unroll
        for (int k = 0; k < 8; ++k) {
          o0[k] = f2bf(vv[k] + ax[k]); o1[k] = f2bf(vv[8 + k] + ax[8 + k]);
        }
        *(u16x8*)&((u16*)Cp)[idx] = o0;
        *(u16x8*)&((u16*)Cp)[idx + 8] = o1;
      } else if (EPI == 4) {               // relu(v + b1) -> bf16
        u16x8 b0 = *(const u16x8*)&bias[colg];
        u16x8 b1 = *(const u16x8*)&bias[colg + 8];
        u16x8 o0, o1;
#pragma unroll
        for (int k = 0; k < 8; ++k) {
          o0[k] = f2bf(fmaxf(vv[k] + bf2f(b0[k]), 0.f));
          o1[k] = f2bf(fmaxf(vv[8 + k] + bf2f(b1[k]), 0.f));
        }
        *(u16x8*)&((u16*)Cp)[idx] = o0;
        *(u16x8*)&((u16*)Cp)[idx + 8] = o1;
      } else {                             // EPI 5: out = h(bf16) + v + b2
        u16x8 b0 = *(const u16x8*)&bias[colg];
        u16x8 b1 = *(const u16x8*)&bias[colg + 8];
        u16x8 a0 = *(const u16x8*)&addbf[idx];
        u16x8 a1 = *(const u16x8*)&addbf[idx + 8];
        float r0[8], r1[8];
#pragma unroll
        for (int k = 0; k < 8; ++k) {
          r0[k] = vv[k] + bf2f(b0[k]) + bf2f(a0[k]);
          r1[k] = vv[8 + k] + bf2f(b1[k]) + bf2f(a1[k]);
        }
        if (fl) {
          f32x4 f0, f1, f2, f3;
#pragma unroll
          for (int k = 0; k < 4; ++k) { f0[k] = r0[k]; f1[k] = r0[4 + k]; f2[k] = r1[k]; f3[k] = r1[4 + k]; }
          *(f32x4*)&((float*)Cp)[idx] = f0;
          *(f32x4*)&((float*)Cp)[idx + 4] = f1;
          *(f32x4*)&((float*)Cp)[idx + 8] = f2;
          *(f32x4*)&((float*)Cp)[idx + 12] = f3;
        } else {
          u16x8 o0, o1;
#pragma unroll
          for (int k = 0; k < 8; ++k) { o0[k] = f2bf(r0[k]); o1[k] = f2bf(r1[k]); }
          *(u16x8*)&((u16*)Cp)[idx] = o0;
          *(u16x8*)&((u16*)Cp)[idx + 8] = o1;
        }
      }
    }
  }
}

// ---------------------------------------------------------------------------
// x_proj split-K: part[z] = u[:, z*256:(z+1)*256] @ w_xproj[:, same]^T
// grid (8, 64). Output f32 partials [8, NTOK, 68]. Round-8 dbuf pipeline,
// scalar guarded epilogue (only 68 of 128 cols are live).
// ---------------------------------------------------------------------------
__global__ __launch_bounds__(256, 2)
void xproj_splitk(const u16* __restrict__ A, const u16* __restrict__ Bc,
                  const u16* __restrict__ Braw, const int* __restrict__ dtflag,
                  float* __restrict__ part)
{
  __shared__ __align__(16) u16 sA[2][128 * 32];
  __shared__ __align__(16) u16 sB[2][128 * 32];
  const int fl = *dtflag;
  const u16* __restrict__ B = fl ? Bc : Braw;
  const int tid = threadIdx.x;
  const int kz = blockIdx.x;           // 0..7
  const int m0 = blockIdx.y * 128;
  const int kbase = kz * 256;
  const int lane = tid & 63;
  const int wv = tid >> 6;
  const int wm = (wv & 1) * 64;
  const int wn = (wv >> 1) * 64;
  const int r = lane & 15;
  const int q = lane >> 4;
  const int rsw = (r >> 1) & 3;
  const int pr = lane >> 2;
  const int kc = (lane & 3) ^ ((pr >> 1) & 3);
  const int pk = kc * 8;

  u16* lA0[2] = { &sA[0][(wv * 2 + 0) * 512], &sA[1][(wv * 2 + 0) * 512] };
  u16* lA1[2] = { &sA[0][(wv * 2 + 1) * 512], &sA[1][(wv * 2 + 1) * 512] };
  u16* lB0[2] = { &sB[0][(wv * 2 + 0) * 512], &sB[1][(wv * 2 + 0) * 512] };
  u16* lB1[2] = { &sB[0][(wv * 2 + 1) * 512], &sB[1][(wv * 2 + 1) * 512] };
  int br0 = wv * 32 + pr;      if (br0 > 67) br0 = 67;   // junk cols unused
  int br1 = wv * 32 + 16 + pr; if (br1 > 67) br1 = 67;
  const u16* gA0 = A + (size_t)(m0 + wv * 32 + pr) * DI + kbase + pk;
  const u16* gA1 = gA0 + (size_t)16 * DI;
  const u16* gB0 = B + (size_t)br0 * DI + kbase + pk;
  const u16* gB1 = B + (size_t)br1 * DI + kbase + pk;

  f32x4 acc[4][4];
#pragma unroll
  for (int i = 0; i < 4; ++i)
#pragma unroll
    for (int j = 0; j < 4; ++j)
#pragma unroll
      for (int t = 0; t < 4; ++t) acc[i][j][t] = 0.f;

  g2l16(gA0, lA0[0]); g2l16(gA1, lA1[0]);
  g2l16(gB0, lB0[0]); g2l16(gB1, lB1[0]);

  for (int kt = 0; kt < 8; ++kt) {
    const int cur = kt & 1;
    __syncthreads();
    bf16x8 af[4], bfr[4];
#pragma unroll
    for (int i = 0; i < 4; ++i)
      af[i] = *reinterpret_cast<const bf16x8*>(
          &sA[cur][(wm + i * 16 + r) * 32 + (q ^ rsw) * 8]);
#pragma unroll
    for (int j = 0; j < 4; ++j)
      bfr[j] = *reinterpret_cast<const bf16x8*>(
          &sB[cur][(wn + j * 16 + r) * 32 + (q ^ rsw) * 8]);
    if (kt + 1 < 8) {
      gA0 += 32; gA1 += 32; gB0 += 32; gB1 += 32;
      g2l16(gA0, lA0[cur ^ 1]); g2l16(gA1, lA1[cur ^ 1]);
      g2l16(gB0, lB0[cur ^ 1]); g2l16(gB1, lB1[cur ^ 1]);
    }
#pragma unroll
    for (int i = 0; i < 4; ++i)
#pragma unroll
      for (int j = 0; j < 4; ++j)
        acc[i][j] = __builtin_amdgcn_mfma_f32_16x16x32_bf16(af[i], bfr[j], acc[i][j], 0, 0, 0);
  }

#pragma unroll
  for (int i = 0; i < 4; ++i)
#pragma unroll
    for (int j = 0; j < 4; ++j)
#pragma unroll
      for (int t = 0; t < 4; ++t) {
        const int row = m0 + wm + i * 16 + q * 4 + t;
        const int col = wn + j * 16 + r;
        if (col < NXP)
          part[((size_t)kz * NTOK + row) * NXP + col] = acc[i][j][t];
      }
}

// Reduce partials: cols 0..63 -> dtraw bf16 [NTOK,64]; 64..67 -> bc f32 [NTOK,4]
__global__ __launch_bounds__(256)
void xreduce_kernel(const float* __restrict__ part, u16* __restrict__ dtraw,
                    float* __restrict__ bc)
{
  const int i = blockIdx.x * 256 + threadIdx.x;
  if (i >= NTOK * NXP) return;
  const int row = i / NXP, col = i - row * NXP;
  float s = 0.f;
#pragma unroll
  for (int z = 0; z < 8; ++z) s += part[(size_t)z * NTOK * NXP + i];
  if (col < DTR) dtraw[(size_t)row * DTR + col] = f2bf(s);
  else           bc[row * 4 + (col - DTR)] = s;
}

// ---------------------------------------------------------------------------
// Depthwise causal conv (k=4, transposed weights) + bias + SiLU, x8 vectorized.
// ---------------------------------------------------------------------------
__global__ __launch_bounds__(256)
void conv_silu_kernel(const u16* __restrict__ xp, const u16* __restrict__ cwT,
                      const u16* __restrict__ cb, u16* __restrict__ u)
{
  const int token = blockIdx.x;
  const int t = token & (SEQ - 1);
  const int d0 = threadIdx.x * 8;
  const ptrdiff_t base = (ptrdiff_t)token * DI + d0;
  float acc[8];
  u16x8 cbv = *(const u16x8*)(cb + d0);
#pragma unroll
  for (int k = 0; k < 8; ++k) acc[k] = bf2f(cbv[k]);
#pragma unroll
  for (int j = 0; j < 4; ++j) {
    if (t - 3 + j >= 0) {
      u16x8 xv = *(const u16x8*)(xp + base + (ptrdiff_t)(j - 3) * DI);
      u16x8 wv = *(const u16x8*)(cwT + j * DI + d0);
#pragma unroll
      for (int k = 0; k < 8; ++k) acc[k] += bf2f(wv[k]) * bf2f(xv[k]);
    }
  }
  u16x8 o;
#pragma unroll
  for (int k = 0; k < 8; ++k) {
    const float sg = 1.f / (1.f + __expf(-acc[k]));
    o[k] = f2bf(acc[k] * sg);
  }
  *(u16x8*)(u + base) = o;
}

// ---------------------------------------------------------------------------
// Chunked SSM scan (N=2 states), 4 channels per thread, CHUNK=32.
// ---------------------------------------------------------------------------
__global__ __launch_bounds__(256)
void scan_pass1(const u16* __restrict__ dtb, const u16* __restrict__ ub,
                const float* __restrict__ bc, const u16* __restrict__ a_log,
                float* __restrict__ S, float* __restrict__ hf0, float* __restrict__ hf1)
{
  const int g4 = blockIdx.x * 256 + threadIdx.x;   // NCHK*NCH/4
  const int chg = g4 & (NCH / 4 - 1);
  const int c = g4 >> 10;
  const int ch0 = chg * 4;
  const int b = ch0 >> 11;
  const int d0 = ch0 & (DI - 1);
  u16x8 av = *(const u16x8*)(a_log + d0 * 2);
  float A0[4], A1[4];
#pragma unroll
  for (int k = 0; k < 4; ++k) {
    A0[k] = -__expf(bf2f(av[2 * k]));
    A1[k] = -__expf(bf2f(av[2 * k + 1]));
  }
  float h0[4] = {0.f, 0.f, 0.f, 0.f}, h1[4] = {0.f, 0.f, 0.f, 0.f};
  float s[4] = {0.f, 0.f, 0.f, 0.f};
  const int row0 = b * SEQ + c * CHUNK;
  for (int i = 0; i < CHUNK; ++i) {
    const size_t row = row0 + i;
    u16x4 dtv = *(const u16x4*)(dtb + row * DI + d0);
    u16x4 uv  = *(const u16x4*)(ub + row * DI + d0);
    f32x2 Bv = *(const f32x2*)(bc + row * 4);
#pragma unroll
    for (int k = 0; k < 4; ++k) {
      const float dt = bf2f(dtv[k]);
      const float dtu = dt * bf2f(uv[k]);
      h0[k] = __expf(A0[k] * dt) * h0[k] + dtu * Bv[0];
      h1[k] = __expf(A1[k] * dt) * h1[k] + dtu * Bv[1];
      s[k] += dt;
    }
  }
  const size_t g0 = (size_t)c * NCH + ch0;
  *(f32x4*)(S + g0)   = f32x4{s[0], s[1], s[2], s[3]};
  *(f32x4*)(hf0 + g0) = f32x4{h0[0], h0[1], h0[2], h0[3]};
  *(f32x4*)(hf1 + g0) = f32x4{h1[0], h1[1], h1[2], h1[3]};
}

__global__ __launch_bounds__(256)
void scan_pass2(const float* __restrict__ S, const float* __restrict__ hf0,
                const float* __restrict__ hf1, const u16* __restrict__ a_log,
                float* __restrict__ hi0, float* __restrict__ hi1)
{
  const int ch = blockIdx.x * 256 + threadIdx.x;  // NCH
  const int d = ch & (DI - 1);
  const float A0 = -__expf(bf2f(a_log[d * 2 + 0]));
  const float A1 = -__expf(bf2f(a_log[d * 2 + 1]));
  float h0 = 0.f, h1 = 0.f;
  // software-pipelined: prefetch next chunk's state while combining current
  size_t g = ch;
  float sv = S[g], f0 = hf0[g], f1 = hf1[g];
  for (int c = 0; c < NCHK; ++c) {
    float svn = 0.f, f0n = 0.f, f1n = 0.f;
    if (c + 1 < NCHK) {
      const size_t gn = g + NCH;
      svn = S[gn]; f0n = hf0[gn]; f1n = hf1[gn];
    }
    hi0[g] = h0; hi1[g] = h1;
    h0 = __expf(A0 * sv) * h0 + f0;
    h1 = __expf(A1 * sv) * h1 + f1;
    sv = svn; f0 = f0n; f1 = f1n;
    g += NCH;
  }
}

__global__ __launch_bounds__(256)
void scan_pass3(const u16* __restrict__ dtb, const u16* __restrict__ ub,
                const float* __restrict__ bc, const u16* __restrict__ zbuf,
                const u16* __restrict__ a_log, const u16* __restrict__ d_skip,
                const float* __restrict__ hi0, const float* __restrict__ hi1,
                u16* __restrict__ yb)
{
  const int g4 = blockIdx.x * 256 + threadIdx.x;
  const int chg = g4 & (NCH / 4 - 1);
  const int c = g4 >> 10;
  const int ch0 = chg * 4;
  const int b = ch0 >> 11;
  const int d0 = ch0 & (DI - 1);
  u16x8 av = *(const u16x8*)(a_log + d0 * 2);
  u16x4 dkv = *(const u16x4*)(d_skip + d0);
  float A0[4], A1[4], dsk[4];
#pragma unroll
  for (int k = 0; k < 4; ++k) {
    A0[k] = -__expf(bf2f(av[2 * k]));
    A1[k] = -__expf(bf2f(av[2 * k + 1]));
    dsk[k] = bf2f(dkv[k]);
  }
  const size_t g0 = (size_t)c * NCH + ch0;
  f32x4 h0v = *(const f32x4*)(hi0 + g0);
  f32x4 h1v = *(const f32x4*)(hi1 + g0);
  float h0[4], h1[4];
#pragma unroll
  for (int k = 0; k < 4; ++k) { h0[k] = h0v[k]; h1[k] = h1v[k]; }
  const int row0 = b * SEQ + c * CHUNK;
  for (int i = 0; i < CHUNK; ++i) {
    const size_t row = row0 + i;
    u16x4 dtv = *(const u16x4*)(dtb + row * DI + d0);
    u16x4 uv  = *(const u16x4*)(ub + row * DI + d0);
    u16x4 zv  = *(const u16x4*)(zbuf + row * DI + d0);
    f32x4 bcv = *(const f32x4*)(bc + row * 4);
    u16x4 o;
#pragma unroll
    for (int k = 0; k < 4; ++k) {
      const float dt = bf2f(dtv[k]);
      const float uu = bf2f(uv[k]);
      const float dtu = dt * uu;
      h0[k] = __expf(A0[k] * dt) * h0[k] + dtu * bcv[0];
      h1[k] = __expf(A1[k] * dt) * h1[k] + dtu * bcv[1];
      const float y = h0[k] * bcv[2] + h1[k] * bcv[3];
      const float z = bf2f(zv[k]);
      const float sz = z / (1.f + __expf(-z));
      o[k] = f2bf((y + dsk[k] * uu) * sz);
    }
    *(u16x4*)(yb + row * DI + d0) = o;    // in-place over dtb: ok
  }
}

// ---------------------------------------------------------------------------
extern "C" void kernel_launch(void* const* d_in, const int* in_sizes, int n_in,
                              void* d_out, int out_size, void* d_ws, size_t ws_size,
                              hipStream_t stream)
{
  const void* x       = d_in[0];
  const void* w_in    = d_in[1];
  const void* conv_w  = d_in[2];
  const void* conv_b  = d_in[3];
  const void* w_xproj = d_in[4];
  const void* w_dt    = d_in[5];
  const void* b_dt    = d_in[6];
  const void* a_log   = d_in[7];
  const void* d_skip  = d_in[8];
  const void* w_out   = d_in[9];
  const void* ln1_g   = d_in[10];
  const void* ln1_b   = d_in[11];
  const void* ln2_g   = d_in[12];
  const void* ln2_b   = d_in[13];
  const void* ffn_w1  = d_in[14];
  const void* ffn_b1  = d_in[15];
  const void* ffn_w2  = d_in[16];
  const void* ffn_b2  = d_in[17];
  char* ws = (char*)d_ws;

  // ---- workspace layout (high-water ~127 MB) ----
  const size_t o_flag  = 0;
  const size_t o_small = 256;
  const size_t o_cwout = o_small + 65536;
  const size_t o_cff1  = o_cwout + (size_t)DM * DI * 2;
  const size_t o_cff2  = o_cff1  + (size_t)DM * DM * 2;
  const size_t o_cxp   = o_cff2  + (size_t)DM * DM * 2;
  const size_t o_cwdt  = o_cxp   + (size_t)NXP * DI * 2;
  const size_t o_xn    = 9437184;                         // 16 MiB region
  const size_t o_xp    = o_xn + (size_t)NTOK * DM * 2;    // 32 MiB
  const size_t o_z     = o_xp + (size_t)NTOK * DI * 2;    // 32 MiB
  const size_t o_u     = o_z  + (size_t)NTOK * DI * 2;    // 32 MiB
  const size_t o_bc    = o_u  + (size_t)NTOK * DI * 2;    // 128 KiB
  // scan state overlays the xn region (dead during the scan):
  const size_t SCN = (size_t)NCHK * NCH * 4;              // 2 MiB each
  const size_t o_S   = o_xn + 0 * SCN;
  const size_t o_hf0 = o_xn + 1 * SCN;
  const size_t o_hf1 = o_xn + 2 * SCN;
  const size_t o_hi0 = o_xn + 3 * SCN;
  const size_t o_hi1 = o_xn + 4 * SCN;                    // ends +10 MiB < 16 MiB

  int*   flagp   = (int*)(ws + o_flag);
  u16*   csmall  = (u16*)(ws + o_small);
  u16*   c_cwT   = csmall +     0;       // transposed conv weights [4][DI]
  u16*   c_convb = csmall +  8192;
  u16*   c_bdt   = csmall + 10240;
  u16*   c_alog  = csmall + 12288;
  u16*   c_dskip = csmall + 16384;
  u16*   c_ln1g  = csmall + 18432;
  u16*   c_ln1b  = csmall + 19456;
  u16*   c_ln2g  = csmall + 20480;
  u16*   c_ln2b  = csmall + 21504;
  u16*   c_fb1   = csmall + 22528;
  u16*   c_fb2   = csmall + 23552;
  u16*   c_wout  = (u16*)(ws + o_cwout);
  u16*   c_ff1   = (u16*)(ws + o_cff1);
  u16*   c_ff2   = (u16*)(ws + o_cff2);
  u16*   c_xproj = (u16*)(ws + o_cxp);
  u16*   c_wdt   = (u16*)(ws + o_cwdt);
  u16*   c_win   = (u16*)(ws + o_u);     // overlays u (dead until conv)
  u16*   xn      = (u16*)(ws + o_xn);
  u16*   xp      = (u16*)(ws + o_xp);
  u16*   zb      = (u16*)(ws + o_z);
  u16*   u       = (u16*)(ws + o_u);
  float* part    = (float*)(ws + o_xp);  // overlays xp (dead after conv)
  u16*   dtraw   = (u16*)(ws + o_xn);    // overlays xn (dead after in_proj)
  u16*   dtb     = xp;                   // overlays part (dead after reduce)
  u16*   yb      = xp;
  float* bc      = (float*)(ws + o_bc);
  float* S       = (float*)(ws + o_S);   // scan arrays overlay xn region
  float* hf0     = (float*)(ws + o_hf0);
  float* hf1     = (float*)(ws + o_hf1);
  float* hi0     = (float*)(ws + o_hi0);
  float* hi1     = (float*)(ws + o_hi1);
  u16*   hb      = (u16*)(ws + o_z);     // h as bf16, overlays z (dead after pass3)
  u16*   hn      = (u16*)(ws + o_xn);    // overlays scan arrays (dead)
  u16*   f1      = (u16*)(ws + o_u);     // overlays u (dead)

  const dim3 blk(256);

  // 0) detect dtype; all param conversion in ONE launch (no-op weights on bf16)
  detect_kernel<<<1, blk, 0, stream>>>((const u16*)x, flagp);
  convert_all<<<NBB + 96, blk, 0, stream>>>(
      (const float*)w_in, (const float*)w_xproj, (const float*)w_dt,
      (const float*)w_out, (const float*)ffn_w1, (const float*)ffn_w2,
      c_win, c_xproj, c_wdt, c_wout, c_ff1, c_ff2,
      conv_w, conv_b, b_dt, a_log, d_skip,
      ln1_g, ln1_b, ln2_g, ln2_b, ffn_b1, ffn_b2,
      csmall, flagp);

  // 1) LN1(x) -> xn
  ln_kernel<0><<<NTOK / 2, blk, 0, stream>>>(x, c_ln1g, c_ln1b, xn, flagp);
  // 2) fused in_proj: [xp | z] = xn @ w_in^T   (N=4096 -> LNBX=5, 2048 blocks)
  gemm_kernel<6, 5><<<2048, blk, 0, stream>>>(xn, c_win, (const u16*)w_in,
                                              NTOK, 2 * DI, DM,
                                              nullptr, nullptr, nullptr, flagp, xp, zb);
  // 3) u = silu(conv(xp) + conv_b)
  conv_silu_kernel<<<NTOK, blk, 0, stream>>>(xp, c_cwT, c_convb, u);
  // 4) x_proj split-K (partials) + reduce -> dtraw (bf16), bc (f32)
  xproj_splitk<<<dim3(8, 64), blk, 0, stream>>>(u, c_xproj, (const u16*)w_xproj,
                                                flagp, part);
  xreduce_kernel<<<(NTOK * NXP + 255) / 256, blk, 0, stream>>>(part, dtraw, bc);
  // 5) dt = softplus(dtraw @ w_dt^T + b_dt)   (N=2048 -> LNBX=4, K=64 -> nk=2)
  gemm_kernel<2, 4><<<1024, blk, 0, stream>>>(dtraw, c_wdt, (const u16*)w_dt,
                                              NTOK, DI, DTR,
                                              c_bdt, nullptr, nullptr, flagp, dtb, nullptr);
  // 6) chunked scan -> yb = (y + d_skip*u) * silu(z)
  scan_pass1<<<NCHK * NCH / 4 / 256, blk, 0, stream>>>(dtb, u, bc, c_alog, S, hf0, hf1);
  scan_pass2<<<NCH / 256, blk, 0, stream>>>(S, hf0, hf1, c_alog, hi0, hi1);
  scan_pass3<<<NCHK * NCH / 4 / 256, blk, 0, stream>>>(dtb, u, bc, zb, c_alog, c_dskip,
                                                       hi0, hi1, yb);
  // 7) h = bf16(x + yb @ w_out^T)   (N=1024 -> LNBX=3)
  gemm_kernel<3, 3><<<512, blk, 0, stream>>>(yb, c_wout, (const u16*)w_out,
                                             NTOK, DM, DI,
                                             nullptr, (const u16*)x, (const float*)x,
                                             flagp, hb, nullptr);
  // 8) LN2(h) -> hn   (bf16 input)
  ln_kernel<1><<<NTOK / 2, blk, 0, stream>>>(hb, c_ln2g, c_ln2b, hn, flagp);
  // 9) f1 = relu(hn @ ffn_w1^T + b1)
  gemm_kernel<4, 3><<<512, blk, 0, stream>>>(hn, c_ff1, (const u16*)ffn_w1,
                                             NTOK, DM, DM,
                                             c_fb1, nullptr, nullptr, flagp, f1, nullptr);
  // 10) out = h + f1 @ ffn_w2^T + b2   (h read as bf16)
  gemm_kernel<5, 3><<<512, blk, 0, stream>>>(f1, c_ff2, (const u16*)ffn_w2,
                                             NTOK, DM, DM,
                                             c_fb2, hb, nullptr, flagp, d_out, nullptr);
}